// Round 6
// baseline (1699.674 us; speedup 1.0000x reference)
//
#include <hip/hip_runtime.h>
#include <hip/hip_bf16.h>

typedef __bf16 bf16;
typedef __bf16 bf16x8 __attribute__((ext_vector_type(8)));
typedef float f32x4 __attribute__((ext_vector_type(4)));
typedef unsigned int u32;

#define PHI_SCALE  0.31947154f   // 96^-0.25
#define DIAG_SCALE 0.05103104f   // 0.5 * 96^-0.5
#define FEAT_SCALE 0.0625f       // 256^-0.5

// async global->LDS, 16B per lane; LDS dest = wave-uniform base + lane*16
__device__ __forceinline__ void glds16(const bf16* g, bf16* l) {
  __builtin_amdgcn_global_load_lds(
      (const __attribute__((address_space(1))) u32*)g,
      (__attribute__((address_space(3))) u32*)l, 16, 0, 0);
}

// XCD-aware 2D block swizzle (4 XCDs along M, 2 along N). Each XCD owns a
// contiguous (M/4 x N/2) region. Requires nbx%4==0, nby%2==0.
__device__ __forceinline__ void xcd_remap(int& bx, int& by) {
  int nbx = gridDim.x, nby = gridDim.y;
  int lin = bx + nbx * by;
  int xcd = lin & 7, idx = lin >> 3;
  int mloc = nbx >> 2, nloc = nby >> 1;
  int xm = xcd & 3, xn = xcd >> 2;
  bx = xm * mloc + (idx % mloc);
  by = xn * nloc + (idx / mloc);
}

// LDS bank swizzle (R4 measured: SQ_LDS_BANK_CONFLICT 3.5M -> 0 with this pair).
__device__ __forceinline__ int swz_scol(int lane) {   // stage: source col in elems
  return (((lane & 3) ^ ((lane >> 3) & 3)) * 8);
}

// ---------------- reductions ----------------
__device__ __forceinline__ float waveSum(float v) {
#pragma unroll
  for (int o = 32; o > 0; o >>= 1) v += __shfl_xor(v, o, 64);
  return v;
}
__device__ __forceinline__ float waveMax(float v) {
#pragma unroll
  for (int o = 32; o > 0; o >>= 1) v = fmaxf(v, __shfl_xor(v, o, 64));
  return v;
}
__device__ __forceinline__ float blockSum(float v) {
  __shared__ float tmp[4];
  v = waveSum(v);
  if ((threadIdx.x & 63) == 0) tmp[threadIdx.x >> 6] = v;
  __syncthreads();
  float r = tmp[0] + tmp[1] + tmp[2] + tmp[3];
  __syncthreads();
  return r;
}
__device__ __forceinline__ float blockMax(float v) {
  __shared__ float tmp[4];
  v = waveMax(v);
  if ((threadIdx.x & 63) == 0) tmp[threadIdx.x >> 6] = v;
  __syncthreads();
  float r = fmaxf(fmaxf(tmp[0], tmp[1]), fmaxf(tmp[2], tmp[3]));
  __syncthreads();
  return r;
}

// ---------------- patch gather: mel f32 -> patches bf16 (4096 x 256) ----------------
__global__ __launch_bounds__(256) void patches_kernel(const float* __restrict__ mel,
    bf16* __restrict__ patches) {
  int blk = blockIdx.x, t = threadIdx.x;
  int b = blk >> 9, n = blk & 511;
  int r0 = (n >> 3) << 4, c0 = (n & 7) << 4;
  patches[(size_t)blk * 256 + t] =
      (bf16)mel[((size_t)b * 1024 + r0 + (t >> 4)) * 128 + c0 + (t & 15)];
}

// ---------------- f32 -> bf16 convert ----------------
__global__ __launch_bounds__(256) void cvt_kernel(const float* __restrict__ src,
    bf16* __restrict__ dst, int n) {
  int i = blockIdx.x * 256 + threadIdx.x;
  if (i < n) dst[i] = (bf16)src[i];
}

// ---------------- merged per-layer weight transpose+cvt (4 weights, 1 dispatch) -------
__device__ __forceinline__ void tile_transpose(const float* __restrict__ src,
    bf16* __restrict__ dst, int K, int N, int bx, int by) {
  __shared__ float lds[64][65];
  int n0 = bx * 64, k0 = by * 64;
  int t = threadIdx.x;
  for (int idx = t; idx < 4096; idx += 256) {
    int r = idx >> 6, c = idx & 63;
    lds[r][c] = src[(size_t)(k0 + r) * N + n0 + c];
  }
  __syncthreads();
  for (int idx = t; idx < 4096; idx += 256) {
    int r = idx >> 6, c = idx & 63;
    dst[(size_t)(n0 + r) * K + k0 + c] = (bf16)lds[c][r];
  }
}
__global__ __launch_bounds__(256) void transpose4_kernel(
    const float* __restrict__ w0, bf16* __restrict__ d0,
    const float* __restrict__ w1, bf16* __restrict__ d1,
    const float* __restrict__ w2, bf16* __restrict__ d2,
    const float* __restrict__ w3, bf16* __restrict__ d3) {
  int i = blockIdx.x;
  if (i < 432)       { tile_transpose(w0, d0, 768, 2304, i % 36, i / 36); }          // qkv_w
  else if (i < 576)  { i -= 432;  tile_transpose(w1, d1, 768, 768, i % 12, i / 12); } // ao_w
  else if (i < 1152) { i -= 576;  tile_transpose(w2, d2, 768, 3072, i % 48, i / 48);} // ff1_w
  else               { i -= 1152; tile_transpose(w3, d3, 3072, 768, i % 12, i / 12);} // ff2_w
}

// ---------------- layernorm: x(f32, rows x 768) -> h(bf16) ----------------
__global__ __launch_bounds__(256) void ln_kernel(const float* __restrict__ x,
    const float* __restrict__ s, const float* __restrict__ bta, bf16* __restrict__ h) {
  int row = blockIdx.x;
  const float* xr = x + (size_t)row * 768;
  int t = threadIdx.x;
  float v0 = xr[t], v1 = xr[t + 256], v2 = xr[t + 512];
  float mu = blockSum(v0 + v1 + v2) * (1.f / 768.f);
  float d0 = v0 - mu, d1 = v1 - mu, d2 = v2 - mu;
  float var = blockSum(d0 * d0 + d1 * d1 + d2 * d2) * (1.f / 768.f);
  float inv = rsqrtf(var + 1e-5f);
  bf16* hr = h + (size_t)row * 768;
  hr[t]       = (bf16)(d0 * inv * s[t]       + bta[t]);
  hr[t + 256] = (bf16)(d1 * inv * s[t + 256] + bta[t + 256]);
  hr[t + 512] = (bf16)(d2 * inv * s[t + 512] + bta[t + 512]);
}

// ---------------- big MFMA GEMM: BM=BN=128, BK=64 -----------------------------------
// mode 0: outb=bf16(v); 1: outb=bf16(gelu(v))
__global__ __launch_bounds__(256) void gemm128(const bf16* __restrict__ A,
    const bf16* __restrict__ B, const float* __restrict__ bias,
    bf16* __restrict__ outb, int N, int K, int mode) {
  __shared__ __attribute__((aligned(16))) bf16 lds_a[2 * 128 * 32];
  __shared__ __attribute__((aligned(16))) bf16 lds_b[2 * 128 * 32];
  int bx = blockIdx.x, by = blockIdx.y;
  xcd_remap(bx, by);
  const int t = threadIdx.x;
  const int m0 = bx * 128, n0 = by * 128;
  const int wave = t >> 6, lane = t & 63;
  const int quad = lane >> 4, id = lane & 15;
  const int wr = wave >> 1, wc = wave & 1;
  const int srow = lane >> 2, scol = swz_scol(lane);
  const bf16* pa0 = A + (size_t)(m0 + wave * 32 + srow) * K + scol;
  const bf16* pa1 = pa0 + (size_t)16 * K;
  const bf16* pb0 = B + (size_t)(n0 + wave * 32 + srow) * K + scol;
  const bf16* pb1 = pb0 + (size_t)16 * K;
  bf16* la = lds_a + wave * 1024;
  bf16* lb = lds_b + wave * 1024;
  const int sl = (quad ^ ((id >> 1) & 3)) * 8;   // swizzled read slot
  f32x4 acc[4][4] = {};
  for (int k0 = 0; k0 < K; k0 += 64) {
    glds16(pa0, la);      glds16(pa1, la + 512);
    glds16(pa0 + 32, la + 4096); glds16(pa1 + 32, la + 4096 + 512);
    glds16(pb0, lb);      glds16(pb1, lb + 512);
    glds16(pb0 + 32, lb + 4096); glds16(pb1 + 32, lb + 4096 + 512);
    pa0 += 64; pa1 += 64; pb0 += 64; pb1 += 64;
    __syncthreads();
#pragma unroll
    for (int kh = 0; kh < 2; kh++) {
      bf16x8 af[4], bg[4];
#pragma unroll
      for (int i = 0; i < 4; i++)
        af[i] = *(bf16x8*)&lds_a[kh * 4096 + (wr * 64 + i * 16 + id) * 32 + sl];
#pragma unroll
      for (int j = 0; j < 4; j++)
        bg[j] = *(bf16x8*)&lds_b[kh * 4096 + (wc * 64 + j * 16 + id) * 32 + sl];
#pragma unroll
      for (int i = 0; i < 4; i++)
#pragma unroll
        for (int j = 0; j < 4; j++)
          acc[i][j] = __builtin_amdgcn_mfma_f32_16x16x32_bf16(af[i], bg[j], acc[i][j], 0, 0, 0);
    }
    __syncthreads();
  }
#pragma unroll
  for (int i = 0; i < 4; i++) {
#pragma unroll
    for (int j = 0; j < 4; j++) {
#pragma unroll
      for (int r = 0; r < 4; r++) {
        int rr = m0 + wr * 64 + i * 16 + quad * 4 + r;
        int cc = n0 + wc * 64 + j * 16 + id;
        float v = acc[i][j][r] + bias[cc];
        if (mode == 1) v = 0.5f * v * (1.0f + erff(v * 0.70710678f));
        outb[(size_t)rr * N + cc] = (bf16)v;
      }
    }
  }
}

// ---------------- MFMA GEMM: BM=128, BN=64, BK=64 -----------------------------------
// mode 0: outb=bf16(v); 1: outb=bf16(gelu(v)); 3: xout=v+pos; 4: atomicAdd(xout, v)
// R5 post-mortem: five sync structures all pinned at ~9 TB/s tile-read service
// with 3 blocks/CU (grid-limited). Split-K raised to 4 by callers -> 6 blocks/CU
// (LDS 24KB permits 6) -> 2x outstanding loads per CU for latency/BW overlap.
__global__ __launch_bounds__(256) void gemm_b64(const bf16* __restrict__ A,
    const bf16* __restrict__ B, const float* __restrict__ bias,
    bf16* __restrict__ outb, float* __restrict__ xout,
    const float* __restrict__ pos, int N, int kchunk, int mode) {
  __shared__ __attribute__((aligned(16))) bf16 lds_a[2 * 128 * 32];
  __shared__ __attribute__((aligned(16))) bf16 lds_b[2 * 64 * 32];
  int bx = blockIdx.x, by = blockIdx.y;
  xcd_remap(bx, by);
  const int t = threadIdx.x;
  const int m0 = bx * 128, n0 = by * 64;
  const int kz = blockIdx.z;
  const int k_start = kz * kchunk;
  const int wave = t >> 6, lane = t & 63;
  const int quad = lane >> 4, id = lane & 15;
  const int srow = lane >> 2, scol = swz_scol(lane);
  const int K = kchunk * gridDim.z;
  const bf16* pa0 = A + (size_t)(m0 + wave * 32 + srow) * K + k_start + scol;
  const bf16* pa1 = pa0 + (size_t)16 * K;
  const bf16* pb  = B + (size_t)(n0 + wave * 16 + srow) * K + k_start + scol;
  bf16* la = lds_a + wave * 1024;
  bf16* lb = lds_b + wave * 512;
  const int sl = (quad ^ ((id >> 1) & 3)) * 8;   // swizzled read slot
  f32x4 acc[2][4] = {};
  for (int k0 = 0; k0 < kchunk; k0 += 64) {
    glds16(pa0, la);      glds16(pa1, la + 512);
    glds16(pa0 + 32, la + 4096); glds16(pa1 + 32, la + 4096 + 512);
    glds16(pb, lb);       glds16(pb + 32, lb + 2048);
    pa0 += 64; pa1 += 64; pb += 64;
    __syncthreads();
#pragma unroll
    for (int kh = 0; kh < 2; kh++) {
      bf16x8 af[2], bg[4];
#pragma unroll
      for (int i = 0; i < 2; i++)
        af[i] = *(bf16x8*)&lds_a[kh * 4096 + (wave * 32 + i * 16 + id) * 32 + sl];
#pragma unroll
      for (int j = 0; j < 4; j++)
        bg[j] = *(bf16x8*)&lds_b[kh * 2048 + (j * 16 + id) * 32 + sl];
#pragma unroll
      for (int i = 0; i < 2; i++)
#pragma unroll
        for (int j = 0; j < 4; j++)
          acc[i][j] = __builtin_amdgcn_mfma_f32_16x16x32_bf16(af[i], bg[j], acc[i][j], 0, 0, 0);
    }
    __syncthreads();
  }
#pragma unroll
  for (int i = 0; i < 2; i++) {
#pragma unroll
    for (int j = 0; j < 4; j++) {
#pragma unroll
      for (int r = 0; r < 4; r++) {
        int rr = m0 + wave * 32 + i * 16 + quad * 4 + r;
        int cc = n0 + j * 16 + id;
        if (mode == 4) {
          float v = acc[i][j][r] + (kz == 0 ? bias[cc] : 0.f);
          atomicAdd(&xout[(size_t)rr * N + cc], v);
        } else {
          float v = acc[i][j][r] + bias[cc];
          if (mode == 0) {
            outb[(size_t)rr * N + cc] = (bf16)v;
          } else if (mode == 1) {
            outb[(size_t)rr * N + cc] = (bf16)(0.5f * v * (1.0f + erff(v * 0.70710678f)));
          } else {
            xout[(size_t)rr * N + cc] = v + pos[(size_t)(rr & 511) * 768 + cc];
          }
        }
      }
    }
  }
}

// ---------------- fused phi_q: u=qs@proj^T, diag from sumsq, row-max, exp -> pq bf16 ----
__global__ __launch_bounds__(256) void phi_q_kernel(const bf16* __restrict__ qkv,
    const bf16* __restrict__ proj, bf16* __restrict__ pq) {
  __shared__ __attribute__((aligned(16))) bf16 lA[3][64 * 32];
  __shared__ __attribute__((aligned(16))) bf16 lB[3][256 * 32];
  __shared__ float sqlds[64];
  const int t = threadIdx.x;
  const int nt = blockIdx.x, bh = blockIdx.y;
  const int b = bh >> 3, h = bh & 7;
  const int n0 = nt * 64;
  const bf16* Abase = qkv + ((size_t)(b * 512 + n0)) * 2304 + h * 96;
#pragma unroll
  for (int c = 0; c < 3; c++) {
    int v = c * 256 + t;
    int row = v / 12, s = v % 12;
    *(bf16x8*)&lA[s >> 2][row * 32 + (s & 3) * 8] = *(const bf16x8*)&Abase[(size_t)row * 2304 + s * 8];
  }
#pragma unroll
  for (int c = 0; c < 12; c++) {
    int v = c * 256 + t;
    int row = v / 12, s = v % 12;
    *(bf16x8*)&lB[s >> 2][row * 32 + (s & 3) * 8] = *(const bf16x8*)&proj[(size_t)row * 96 + s * 8];
  }
  __syncthreads();
  const int wave = t >> 6, lane = t & 63, quad = lane >> 4, id = lane & 15;
  f32x4 acc[16] = {};
  float sq = 0.f;
#pragma unroll
  for (int kb = 0; kb < 3; kb++) {
    bf16x8 af = *(bf16x8*)&lA[kb][(wave * 16 + id) * 32 + quad * 8];
#pragma unroll
    for (int e = 0; e < 8; e++) { float fv = (float)af[e]; sq += fv * fv; }
#pragma unroll
    for (int j = 0; j < 16; j++) {
      bf16x8 bg = *(bf16x8*)&lB[kb][(j * 16 + id) * 32 + quad * 8];
      acc[j] = __builtin_amdgcn_mfma_f32_16x16x32_bf16(af, bg, acc[j], 0, 0, 0);
    }
  }
  sq += __shfl_xor(sq, 16, 64);
  sq += __shfl_xor(sq, 32, 64);
  if (quad == 0) sqlds[wave * 16 + id] = sq;
  __syncthreads();
#pragma unroll
  for (int r = 0; r < 4; r++) {
    int rrow = quad * 4 + r;
    float dg = DIAG_SCALE * sqlds[wave * 16 + rrow];
    float mx = -1e30f;
#pragma unroll
    for (int j = 0; j < 16; j++) mx = fmaxf(mx, acc[j][r]);
    mx = fmaxf(mx, __shfl_xor(mx, 1, 64));
    mx = fmaxf(mx, __shfl_xor(mx, 2, 64));
    mx = fmaxf(mx, __shfl_xor(mx, 4, 64));
    mx = fmaxf(mx, __shfl_xor(mx, 8, 64));
    float umax = mx * PHI_SCALE;
#pragma unroll
    for (int j = 0; j < 16; j++) {
      float uu = acc[j][r] * PHI_SCALE;
      float val = (expf(uu - dg - umax) + 1e-4f) * FEAT_SCALE;
      pq[((size_t)bh * 512 + n0 + wave * 16 + rrow) * 256 + j * 16 + id] = (bf16)val;
    }
  }
}

// ---------------- fused phi_k: u, diag, block-max; writes pkT TRANSPOSED directly -----
// pkT[bh][m][n] = exp(u - diag - blkmax)  (raw, unrescaled); kbm[bh*8+nt] = blkmax.
// The rescale (factor+1e-4)*FEAT_SCALE is folded into ctx_gemm (factor is uniform
// per 32-wide k chunk there). Kills the pkt pass: -32MB traffic, -1 dispatch/layer.
__global__ __launch_bounds__(256) void phi_k_kernel(const bf16* __restrict__ qkv,
    const bf16* __restrict__ proj, bf16* __restrict__ pkT, float* __restrict__ kbm) {
  __shared__ __attribute__((aligned(16))) bf16 lA[3][64 * 32];
  __shared__ __attribute__((aligned(16))) bf16 lB[3][256 * 32];
  __shared__ float sqlds[64];
  __shared__ float bmax4[4];
  const int t = threadIdx.x;
  const int nt = blockIdx.x, bh = blockIdx.y;
  const int b = bh >> 3, h = bh & 7;
  const int n0 = nt * 64;
  const bf16* Abase = qkv + ((size_t)(b * 512 + n0)) * 2304 + 768 + h * 96;
#pragma unroll
  for (int c = 0; c < 3; c++) {
    int v = c * 256 + t;
    int row = v / 12, s = v % 12;
    *(bf16x8*)&lA[s >> 2][row * 32 + (s & 3) * 8] = *(const bf16x8*)&Abase[(size_t)row * 2304 + s * 8];
  }
#pragma unroll
  for (int c = 0; c < 12; c++) {
    int v = c * 256 + t;
    int row = v / 12, s = v % 12;
    *(bf16x8*)&lB[s >> 2][row * 32 + (s & 3) * 8] = *(const bf16x8*)&proj[(size_t)row * 96 + s * 8];
  }
  __syncthreads();
  const int wave = t >> 6, lane = t & 63, quad = lane >> 4, id = lane & 15;
  f32x4 acc[16] = {};
  float sq = 0.f;
#pragma unroll
  for (int kb = 0; kb < 3; kb++) {
    bf16x8 af = *(bf16x8*)&lA[kb][(wave * 16 + id) * 32 + quad * 8];
#pragma unroll
    for (int e = 0; e < 8; e++) { float fv = (float)af[e]; sq += fv * fv; }
#pragma unroll
    for (int j = 0; j < 16; j++) {
      bf16x8 bg = *(bf16x8*)&lB[kb][(j * 16 + id) * 32 + quad * 8];
      acc[j] = __builtin_amdgcn_mfma_f32_16x16x32_bf16(af, bg, acc[j], 0, 0, 0);
    }
  }
  sq += __shfl_xor(sq, 16, 64);
  sq += __shfl_xor(sq, 32, 64);
  if (quad == 0) sqlds[wave * 16 + id] = sq;
  float bm = -1e30f;
#pragma unroll
  for (int j = 0; j < 16; j++)
#pragma unroll
    for (int r = 0; r < 4; r++) bm = fmaxf(bm, acc[j][r]);
  bm = waveMax(bm);
  if (lane == 0) bmax4[wave] = bm;
  __syncthreads();   // also guarantees all waves' MFMA reads of lB are done
  float blkmax = fmaxf(fmaxf(bmax4[0], bmax4[1]), fmaxf(bmax4[2], bmax4[3])) * PHI_SCALE;
  if (t == 0) kbm[bh * 8 + nt] = blkmax;
  // transpose through LDS (reuse dead lB: need 256x66 bf16 = 33.8KB <= 48KB)
  bf16* sT = &lB[0][0];
#pragma unroll
  for (int r = 0; r < 4; r++) {
    int rrow = wave * 16 + quad * 4 + r;          // n within tile
    float dg = DIAG_SCALE * sqlds[rrow];
#pragma unroll
    for (int j = 0; j < 16; j++) {
      float uu = acc[j][r] * PHI_SCALE;
      sT[(j * 16 + id) * 66 + rrow] = (bf16)expf(uu - dg - blkmax);
    }
  }
  __syncthreads();
  bf16* dst = pkT + ((size_t)bh * 256) * 512 + n0;
#pragma unroll
  for (int it = 0; it < 64; it++) {
    int idx = it * 256 + t;
    int m = idx >> 6, n = idx & 63;
    dst[(size_t)m * 512 + n] = sT[m * 66 + n];
  }
}

// ---------------- vT[bh,e,n] = qkv[b,n,1536+h*96+e] ----------------
__global__ __launch_bounds__(256) void vt_kernel(const bf16* __restrict__ qkv, bf16* __restrict__ vT) {
  __shared__ bf16 lds[64][97];
  int bh = blockIdx.y, b = bh >> 3, h = bh & 7;
  int n0 = blockIdx.x * 64;
  int t = threadIdx.x;
  const bf16* src = qkv + ((size_t)b * 512 + n0) * 2304 + 1536 + h * 96;
  for (int idx = t; idx < 6144; idx += 256) {
    int r = idx / 96, c = idx % 96;
    lds[r][c] = src[(size_t)r * 2304 + c];
  }
  __syncthreads();
  bf16* dst = vT + (size_t)bh * 96 * 512 + n0;
  for (int idx = t; idx < 6144; idx += 256) {
    int e = idx >> 6, nn = idx & 63;
    dst[(size_t)e * 512 + nn] = lds[nn][e];
  }
}

// ---------------- ctx GEMM + fused rescale + ksum -----------------------------------
// A = pkT (raw exp values); applies pk = raw*factor(nt)*FEAT + 1e-4*FEAT on the
// A-fragment before MFMA (factor uniform per 32-wide k chunk: nt = k0>>6).
// gmax computed inline from kbm[512] (2KB, L2-hit).
__global__ __launch_bounds__(256) void ctx_gemm(const bf16* __restrict__ pkT,
    const bf16* __restrict__ vT, const float* __restrict__ kbm,
    bf16* __restrict__ ctxT, float* __restrict__ ksum) {
  __shared__ __attribute__((aligned(16))) bf16 lds_a[64 * 40];
  __shared__ __attribute__((aligned(16))) bf16 lds_b[96 * 40];
  const int t = threadIdx.x;
  const int bh = blockIdx.y, m0 = blockIdx.x * 64;
  const bf16* A = pkT + (size_t)bh * 256 * 512;
  const bf16* B = vT + (size_t)bh * 96 * 512;
  const int wave = t >> 6, lane = t & 63;
  const int quad = lane >> 4, id = lane & 15;
  const int row = t >> 2, kof = (t & 3) * 8;
  float gm = blockMax(fmaxf(kbm[t], kbm[t + 256]));
  f32x4 acc[6] = {};
  float ks = 0.f;
  const float offc = 1e-4f * FEAT_SCALE;
  for (int k0 = 0; k0 < 512; k0 += 32) {
    float fs = expf(kbm[bh * 8 + (k0 >> 6)] - gm) * FEAT_SCALE;
    *(bf16x8*)&lds_a[row * 40 + kof] = *(const bf16x8*)&A[(size_t)(m0 + row) * 512 + k0 + kof];
    for (int idx = t; idx < 384; idx += 256) {
      int r2 = idx >> 2, k2 = (idx & 3) * 8;
      *(bf16x8*)&lds_b[r2 * 40 + k2] = *(const bf16x8*)&B[(size_t)r2 * 512 + k0 + k2];
    }
    __syncthreads();
    bf16x8 af = *(bf16x8*)&lds_a[(wave * 16 + id) * 40 + quad * 8];
    bf16x8 afs;
#pragma unroll
    for (int e = 0; e < 8; e++) {
      float f = (float)af[e] * fs + offc;
      ks += f;
      afs[e] = (bf16)f;
    }
#pragma unroll
    for (int j = 0; j < 6; j++) {
      bf16x8 bg = *(bf16x8*)&lds_b[(j * 16 + id) * 40 + quad * 8];
      acc[j] = __builtin_amdgcn_mfma_f32_16x16x32_bf16(afs, bg, acc[j], 0, 0, 0);
    }
    __syncthreads();
  }
  ks += __shfl_xor(ks, 16, 64);
  ks += __shfl_xor(ks, 32, 64);
  if (quad == 0) ksum[bh * 256 + m0 + wave * 16 + id] = ks;
#pragma unroll
  for (int j = 0; j < 6; j++)
#pragma unroll
    for (int r = 0; r < 4; r++) {
      int e = j * 16 + id;
      int m = m0 + wave * 16 + quad * 4 + r;
      ctxT[((size_t)bh * 96 + e) * 256 + m] = (bf16)acc[j][r];
    }
}

// ---------------- out GEMM + fused den: attn = (pq @ ctxT^T) / (pq . ksum) -------------
__global__ __launch_bounds__(256) void out_gemm(const bf16* __restrict__ pq,
    const bf16* __restrict__ ctxT, const float* __restrict__ ksum, bf16* __restrict__ attn) {
  __shared__ __attribute__((aligned(16))) bf16 lds_a[64 * 40];
  __shared__ __attribute__((aligned(16))) bf16 lds_b[96 * 40];
  __shared__ float den_lds[64];
  const int t = threadIdx.x;
  const int bh = blockIdx.y, m0 = blockIdx.x * 64;
  const int b = bh >> 3, h = bh & 7;
  const bf16* A = pq + (size_t)bh * 512 * 256;
  const bf16* B = ctxT + (size_t)bh * 96 * 256;
  const int wave = t >> 6, lane = t & 63;
  const int quad = lane >> 4, id = lane & 15;
  const int row = t >> 2, kof = (t & 3) * 8;
  f32x4 acc[6] = {};
  float den = 0.f;
  for (int k0 = 0; k0 < 256; k0 += 32) {
    *(bf16x8*)&lds_a[row * 40 + kof] = *(const bf16x8*)&A[(size_t)(m0 + row) * 256 + k0 + kof];
    for (int idx = t; idx < 384; idx += 256) {
      int r2 = idx >> 2, k2 = (idx & 3) * 8;
      *(bf16x8*)&lds_b[r2 * 40 + k2] = *(const bf16x8*)&B[(size_t)r2 * 256 + k0 + k2];
    }
    __syncthreads();
    bf16x8 af = *(bf16x8*)&lds_a[(wave * 16 + id) * 40 + quad * 8];
    const f32x4* kp = (const f32x4*)(ksum + bh * 256 + k0 + quad * 8);
    f32x4 k0v = kp[0], k1v = kp[1];
#pragma unroll
    for (int e = 0; e < 4; e++) den += (float)af[e] * k0v[e];
#pragma unroll
    for (int e = 0; e < 4; e++) den += (float)af[e + 4] * k1v[e];
#pragma unroll
    for (int j = 0; j < 6; j++) {
      bf16x8 bg = *(bf16x8*)&lds_b[(j * 16 + id) * 40 + quad * 8];
      acc[j] = __builtin_amdgcn_mfma_f32_16x16x32_bf16(af, bg, acc[j], 0, 0, 0);
    }
    __syncthreads();
  }
  den += __shfl_xor(den, 16, 64);
  den += __shfl_xor(den, 32, 64);
  if (quad == 0) den_lds[wave * 16 + id] = den;
  __syncthreads();
#pragma unroll
  for (int j = 0; j < 6; j++)
#pragma unroll
    for (int r = 0; r < 4; r++) {
      int e = j * 16 + id;
      int n = m0 + wave * 16 + quad * 4 + r;
      float v = acc[j][r] / fmaxf(den_lds[wave * 16 + quad * 4 + r], 1e-30f);
      attn[((size_t)(b * 512 + n)) * 768 + h * 96 + e] = (bf16)v;
    }
}

// ---------------- final head ----------------
__global__ __launch_bounds__(256) void mask_kernel(const float* __restrict__ x,
    const float* __restrict__ mw, const float* __restrict__ mb, float* __restrict__ out) {
  int row = blockIdx.x * 4 + (threadIdx.x >> 6);
  int lane = threadIdx.x & 63;
  int b = row >> 9, n = row & 511;
  const float* xr = x + (size_t)row * 768;
  float a0 = 0, a1 = 0, a2 = 0, a3 = 0;
  for (int d = lane; d < 768; d += 64) {
    float xv = xr[d];
    a0 += xv * mw[d * 4 + 0];
    a1 += xv * mw[d * 4 + 1];
    a2 += xv * mw[d * 4 + 2];
    a3 += xv * mw[d * 4 + 3];
  }
  a0 = waveSum(a0); a1 = waveSum(a1); a2 = waveSum(a2); a3 = waveSum(a3);
  if (lane == 0) {
    out[((size_t)b * 4 + 0) * 512 + n] = 1.f / (1.f + expf(-(a0 + mb[0])));
    out[((size_t)b * 4 + 1) * 512 + n] = 1.f / (1.f + expf(-(a1 + mb[1])));
    out[((size_t)b * 4 + 2) * 512 + n] = 1.f / (1.f + expf(-(a2 + mb[2])));
    out[((size_t)b * 4 + 3) * 512 + n] = 1.f / (1.f + expf(-(a3 + mb[3])));
  }
}

extern "C" void kernel_launch(void* const* d_in, const int* in_sizes, int n_in,
                              void* d_out, int out_size, void* d_ws, size_t ws_size,
                              hipStream_t stream) {
  const float* mel     = (const float*)d_in[0];
  const float* patch_w = (const float*)d_in[1];
  const float* patch_b = (const float*)d_in[2];
  const float* pos     = (const float*)d_in[3];
  const float* proj    = (const float*)d_in[4];
  const float* ln1_s   = (const float*)d_in[5];
  const float* ln1_b   = (const float*)d_in[6];
  const float* qkv_w   = (const float*)d_in[7];
  const float* qkv_b   = (const float*)d_in[8];
  const float* ao_w    = (const float*)d_in[9];
  const float* ao_b    = (const float*)d_in[10];
  const float* ln2_s   = (const float*)d_in[11];
  const float* ln2_b   = (const float*)d_in[12];
  const float* ff1_w   = (const float*)d_in[13];
  const float* ff1_b   = (const float*)d_in[14];
  const float* ff2_w   = (const float*)d_in[15];
  const float* ff2_b   = (const float*)d_in[16];
  const float* mask_w  = (const float*)d_in[17];
  const float* mask_b  = (const float*)d_in[18];

  char* ws = (char*)d_ws;
  size_t off = 0;
  auto alloc = [&](size_t bytes) { void* p = ws + off; off += (bytes + 255) & ~(size_t)255; return p; };
  float* x     = (float*)alloc(4096ull * 768 * 4);
  bf16* h      = (bf16*)alloc(4096ull * 768 * 2);
  bf16* qkv    = (bf16*)alloc(4096ull * 2304 * 2);
  bf16* wtq    = (bf16*)alloc(2304ull * 768 * 2);
  bf16* wta    = (bf16*)alloc(768ull * 768 * 2);
  bf16* wtf1   = (bf16*)alloc(3072ull * 768 * 2);
  bf16* wtf2   = (bf16*)alloc(768ull * 3072 * 2);
  bf16* patches= (bf16*)alloc(4096ull * 256 * 2);
  bf16* pwb    = (bf16*)alloc(768ull * 256 * 2);
  bf16* projb  = (bf16*)alloc(256ull * 96 * 2);
  bf16* pq     = (bf16*)alloc(8388608ull * 2);
  bf16* pkT    = (bf16*)alloc(8388608ull * 2);
  bf16* vT     = (bf16*)alloc(64ull * 96 * 512 * 2);
  bf16* ctxT   = (bf16*)alloc(64ull * 96 * 256 * 2);
  float* ksum  = (float*)alloc(64ull * 256 * 4);
  float* kbm   = (float*)alloc(512ull * 4);
  bf16* attn   = (bf16*)alloc(4096ull * 768 * 2);
  bf16* ffh    = (bf16*)alloc(4096ull * 3072 * 2);
  if (ws_size < off) return;  // clean fail instead of corruption

  patches_kernel<<<4096, 256, 0, stream>>>(mel, patches);
  cvt_kernel<<<768, 256, 0, stream>>>(patch_w, pwb, 196608);
  cvt_kernel<<<96, 256, 0, stream>>>(proj, projb, 24576);
  gemm_b64<<<dim3(32, 12), 256, 0, stream>>>(patches, pwb, patch_b, nullptr, x, pos,
                                             768, 256, 3);

  for (int l = 0; l < 6; l++) {
    transpose4_kernel<<<1728, 256, 0, stream>>>(
        qkv_w + (size_t)l * 768 * 2304, wtq,
        ao_w + (size_t)l * 768 * 768, wta,
        ff1_w + (size_t)l * 768 * 3072, wtf1,
        ff2_w + (size_t)l * 3072 * 768, wtf2);

    ln_kernel<<<4096, 256, 0, stream>>>(x, ln1_s + l * 768, ln1_b + l * 768, h);
    // qkv: 128x128 tiles, (32,18) = 576 blocks
    gemm128<<<dim3(32, 18), 256, 0, stream>>>(h, wtq, qkv_b + l * 2304, qkv, 2304, 768, 0);

    phi_q_kernel<<<dim3(8, 64), 256, 0, stream>>>(qkv, projb, pq);
    phi_k_kernel<<<dim3(8, 64), 256, 0, stream>>>(qkv, projb, pkT, kbm);
    vt_kernel<<<dim3(8, 64), 256, 0, stream>>>(qkv, vT);
    ctx_gemm<<<dim3(4, 64), 256, 0, stream>>>(pkT, vT, kbm, ctxT, ksum);
    out_gemm<<<dim3(8, 64), 256, 0, stream>>>(pq, ctxT, ksum, attn);
    // x += attn @ ao_w + ao_b   (split-K=4, atomic accumulate, 1536 blocks = 6/CU)
    gemm_b64<<<dim3(32, 12, 4), 256, 0, stream>>>(attn, wta, ao_b + l * 768, nullptr, x,
                                                  nullptr, 768, 192, 4);

    ln_kernel<<<4096, 256, 0, stream>>>(x, ln2_s + l * 768, ln2_b + l * 768, h);
    // ff1: 128x128 tiles, (32,24) = 768 blocks
    gemm128<<<dim3(32, 24), 256, 0, stream>>>(h, wtf1, ff1_b + l * 3072, ffh, 3072, 768, 1);
    // x += ffh @ ff2_w + ff2_b   (split-K=4, atomic accumulate, 1536 blocks = 6/CU)
    gemm_b64<<<dim3(32, 12, 4), 256, 0, stream>>>(ffh, wtf2, ff2_b + l * 768, nullptr, x,
                                                  nullptr, 768, 768, 4);
  }

  mask_kernel<<<1024, 256, 0, stream>>>(x, mask_w, mask_b, (float*)d_out);
}

// Round 7
// 1376.011 us; speedup vs baseline: 1.2352x; 1.2352x over previous
//
#include <hip/hip_runtime.h>
#include <hip/hip_bf16.h>

typedef __bf16 bf16;
typedef __bf16 bf16x8 __attribute__((ext_vector_type(8)));
typedef float f32x4 __attribute__((ext_vector_type(4)));
typedef unsigned int u32;

#define PHI_SCALE  0.31947154f   // 96^-0.25
#define DIAG_SCALE 0.05103104f   // 0.5 * 96^-0.5
#define FEAT_SCALE 0.0625f       // 256^-0.5

// async global->LDS, 16B per lane; LDS dest = wave-uniform base + lane*16
__device__ __forceinline__ void glds16(const bf16* g, bf16* l) {
  __builtin_amdgcn_global_load_lds(
      (const __attribute__((address_space(1))) u32*)g,
      (__attribute__((address_space(3))) u32*)l, 16, 0, 0);
}

// XCD-aware 2D block swizzle (4 XCDs along M, 2 along N). Each XCD owns a
// contiguous (M/4 x N/2) region. Requires nbx%4==0, nby%2==0.
__device__ __forceinline__ void xcd_remap(int& bx, int& by) {
  int nbx = gridDim.x, nby = gridDim.y;
  int lin = bx + nbx * by;
  int xcd = lin & 7, idx = lin >> 3;
  int mloc = nbx >> 2, nloc = nby >> 1;
  int xm = xcd & 3, xn = xcd >> 2;
  bx = xm * mloc + (idx % mloc);
  by = xn * nloc + (idx / mloc);
}

// LDS bank swizzle (R4 measured: SQ_LDS_BANK_CONFLICT 3.5M -> 0 with this pair).
__device__ __forceinline__ int swz_scol(int lane) {   // stage: source col in elems
  return (((lane & 3) ^ ((lane >> 3) & 3)) * 8);
}

// ---------------- reductions ----------------
__device__ __forceinline__ float waveSum(float v) {
#pragma unroll
  for (int o = 32; o > 0; o >>= 1) v += __shfl_xor(v, o, 64);
  return v;
}
__device__ __forceinline__ float waveMax(float v) {
#pragma unroll
  for (int o = 32; o > 0; o >>= 1) v = fmaxf(v, __shfl_xor(v, o, 64));
  return v;
}
__device__ __forceinline__ float blockSum(float v) {
  __shared__ float tmp[4];
  v = waveSum(v);
  if ((threadIdx.x & 63) == 0) tmp[threadIdx.x >> 6] = v;
  __syncthreads();
  float r = tmp[0] + tmp[1] + tmp[2] + tmp[3];
  __syncthreads();
  return r;
}
__device__ __forceinline__ float blockMax(float v) {
  __shared__ float tmp[4];
  v = waveMax(v);
  if ((threadIdx.x & 63) == 0) tmp[threadIdx.x >> 6] = v;
  __syncthreads();
  float r = fmaxf(fmaxf(tmp[0], tmp[1]), fmaxf(tmp[2], tmp[3]));
  __syncthreads();
  return r;
}

// ---------------- patch gather: mel f32 -> patches bf16 (4096 x 256) ----------------
__global__ __launch_bounds__(256) void patches_kernel(const float* __restrict__ mel,
    bf16* __restrict__ patches) {
  int blk = blockIdx.x, t = threadIdx.x;
  int b = blk >> 9, n = blk & 511;
  int r0 = (n >> 3) << 4, c0 = (n & 7) << 4;
  patches[(size_t)blk * 256 + t] =
      (bf16)mel[((size_t)b * 1024 + r0 + (t >> 4)) * 128 + c0 + (t & 15)];
}

// ---------------- f32 -> bf16 convert ----------------
__global__ __launch_bounds__(256) void cvt_kernel(const float* __restrict__ src,
    bf16* __restrict__ dst, int n) {
  int i = blockIdx.x * 256 + threadIdx.x;
  if (i < n) dst[i] = (bf16)src[i];
}

// ---------------- merged per-layer weight transpose+cvt (4 weights, 1 dispatch) -------
__device__ __forceinline__ void tile_transpose(const float* __restrict__ src,
    bf16* __restrict__ dst, int K, int N, int bx, int by) {
  __shared__ float lds[64][65];
  int n0 = bx * 64, k0 = by * 64;
  int t = threadIdx.x;
  for (int idx = t; idx < 4096; idx += 256) {
    int r = idx >> 6, c = idx & 63;
    lds[r][c] = src[(size_t)(k0 + r) * N + n0 + c];
  }
  __syncthreads();
  for (int idx = t; idx < 4096; idx += 256) {
    int r = idx >> 6, c = idx & 63;
    dst[(size_t)(n0 + r) * K + k0 + c] = (bf16)lds[c][r];
  }
}
__global__ __launch_bounds__(256) void transpose4_kernel(
    const float* __restrict__ w0, bf16* __restrict__ d0,
    const float* __restrict__ w1, bf16* __restrict__ d1,
    const float* __restrict__ w2, bf16* __restrict__ d2,
    const float* __restrict__ w3, bf16* __restrict__ d3) {
  int i = blockIdx.x;
  if (i < 432)       { tile_transpose(w0, d0, 768, 2304, i % 36, i / 36); }          // qkv_w
  else if (i < 576)  { i -= 432;  tile_transpose(w1, d1, 768, 768, i % 12, i / 12); } // ao_w
  else if (i < 1152) { i -= 576;  tile_transpose(w2, d2, 768, 3072, i % 48, i / 48);} // ff1_w
  else               { i -= 1152; tile_transpose(w3, d3, 3072, 768, i % 12, i / 12);} // ff2_w
}

// ---------------- layernorm + optional residual fold: x += p0+p1; h = LN(x) ----------
// part != nullptr: consumes the two split-K partial slices (replaces the old
// atomicAdd path -- R6 measured device-scope atomics at ~1us/MB, ~half the
// split-K GEMM time; streaming partials + fused add here removes that).
__global__ __launch_bounds__(256) void ln_kernel(float* __restrict__ x,
    const float* __restrict__ part,
    const float* __restrict__ s, const float* __restrict__ bta, bf16* __restrict__ h) {
  int row = blockIdx.x;
  float* xr = x + (size_t)row * 768;
  int t = threadIdx.x;
  float v0 = xr[t], v1 = xr[t + 256], v2 = xr[t + 512];
  if (part) {
    const float* p0 = part + (size_t)row * 768;
    const float* p1 = p0 + 4096ull * 768;
    v0 += p0[t]       + p1[t];
    v1 += p0[t + 256] + p1[t + 256];
    v2 += p0[t + 512] + p1[t + 512];
    xr[t] = v0; xr[t + 256] = v1; xr[t + 512] = v2;
  }
  float mu = blockSum(v0 + v1 + v2) * (1.f / 768.f);
  float d0 = v0 - mu, d1 = v1 - mu, d2 = v2 - mu;
  float var = blockSum(d0 * d0 + d1 * d1 + d2 * d2) * (1.f / 768.f);
  float inv = rsqrtf(var + 1e-5f);
  bf16* hr = h + (size_t)row * 768;
  hr[t]       = (bf16)(d0 * inv * s[t]       + bta[t]);
  hr[t + 256] = (bf16)(d1 * inv * s[t + 256] + bta[t + 256]);
  hr[t + 512] = (bf16)(d2 * inv * s[t + 512] + bta[t + 512]);
}

// ---------------- big MFMA GEMM: BM=BN=128, BK=64 -----------------------------------
// mode 0: outb=bf16(v); 1: outb=bf16(gelu(v))
__global__ __launch_bounds__(256) void gemm128(const bf16* __restrict__ A,
    const bf16* __restrict__ B, const float* __restrict__ bias,
    bf16* __restrict__ outb, int N, int K, int mode) {
  __shared__ __attribute__((aligned(16))) bf16 lds_a[2 * 128 * 32];
  __shared__ __attribute__((aligned(16))) bf16 lds_b[2 * 128 * 32];
  int bx = blockIdx.x, by = blockIdx.y;
  xcd_remap(bx, by);
  const int t = threadIdx.x;
  const int m0 = bx * 128, n0 = by * 128;
  const int wave = t >> 6, lane = t & 63;
  const int quad = lane >> 4, id = lane & 15;
  const int wr = wave >> 1, wc = wave & 1;
  const int srow = lane >> 2, scol = swz_scol(lane);
  const bf16* pa0 = A + (size_t)(m0 + wave * 32 + srow) * K + scol;
  const bf16* pa1 = pa0 + (size_t)16 * K;
  const bf16* pb0 = B + (size_t)(n0 + wave * 32 + srow) * K + scol;
  const bf16* pb1 = pb0 + (size_t)16 * K;
  bf16* la = lds_a + wave * 1024;
  bf16* lb = lds_b + wave * 1024;
  const int sl = (quad ^ ((id >> 1) & 3)) * 8;   // swizzled read slot
  f32x4 acc[4][4] = {};
  for (int k0 = 0; k0 < K; k0 += 64) {
    glds16(pa0, la);      glds16(pa1, la + 512);
    glds16(pa0 + 32, la + 4096); glds16(pa1 + 32, la + 4096 + 512);
    glds16(pb0, lb);      glds16(pb1, lb + 512);
    glds16(pb0 + 32, lb + 4096); glds16(pb1 + 32, lb + 4096 + 512);
    pa0 += 64; pa1 += 64; pb0 += 64; pb1 += 64;
    __syncthreads();
#pragma unroll
    for (int kh = 0; kh < 2; kh++) {
      bf16x8 af[4], bg[4];
#pragma unroll
      for (int i = 0; i < 4; i++)
        af[i] = *(bf16x8*)&lds_a[kh * 4096 + (wr * 64 + i * 16 + id) * 32 + sl];
#pragma unroll
      for (int j = 0; j < 4; j++)
        bg[j] = *(bf16x8*)&lds_b[kh * 4096 + (wc * 64 + j * 16 + id) * 32 + sl];
#pragma unroll
      for (int i = 0; i < 4; i++)
#pragma unroll
        for (int j = 0; j < 4; j++)
          acc[i][j] = __builtin_amdgcn_mfma_f32_16x16x32_bf16(af[i], bg[j], acc[i][j], 0, 0, 0);
    }
    __syncthreads();
  }
#pragma unroll
  for (int i = 0; i < 4; i++) {
#pragma unroll
    for (int j = 0; j < 4; j++) {
#pragma unroll
      for (int r = 0; r < 4; r++) {
        int rr = m0 + wr * 64 + i * 16 + quad * 4 + r;
        int cc = n0 + wc * 64 + j * 16 + id;
        float v = acc[i][j][r] + bias[cc];
        if (mode == 1) v = 0.5f * v * (1.0f + erff(v * 0.70710678f));
        outb[(size_t)rr * N + cc] = (bf16)v;
      }
    }
  }
}

// ---------------- MFMA GEMM: BM=128, BN=64, BK=64 -----------------------------------
// mode 0: outb=bf16(v); 1: outb=bf16(gelu(v)); 3: xout=v+pos;
// mode 4: NON-ATOMIC partial write: xout[kz*M*N + rr*N + cc] = v (+bias if kz==0).
//         Consumer (ln_kernel/mask_kernel) folds the partials into x.
__global__ __launch_bounds__(256) void gemm_b64(const bf16* __restrict__ A,
    const bf16* __restrict__ B, const float* __restrict__ bias,
    bf16* __restrict__ outb, float* __restrict__ xout,
    const float* __restrict__ pos, int N, int kchunk, int mode) {
  __shared__ __attribute__((aligned(16))) bf16 lds_a[2 * 128 * 32];
  __shared__ __attribute__((aligned(16))) bf16 lds_b[2 * 64 * 32];
  int bx = blockIdx.x, by = blockIdx.y;
  xcd_remap(bx, by);
  const int t = threadIdx.x;
  const int m0 = bx * 128, n0 = by * 64;
  const int kz = blockIdx.z;
  const int k_start = kz * kchunk;
  const int wave = t >> 6, lane = t & 63;
  const int quad = lane >> 4, id = lane & 15;
  const int srow = lane >> 2, scol = swz_scol(lane);
  const int K = kchunk * gridDim.z;
  const size_t slice = (size_t)kz * gridDim.x * 128 * N;
  const bf16* pa0 = A + (size_t)(m0 + wave * 32 + srow) * K + k_start + scol;
  const bf16* pa1 = pa0 + (size_t)16 * K;
  const bf16* pb  = B + (size_t)(n0 + wave * 16 + srow) * K + k_start + scol;
  bf16* la = lds_a + wave * 1024;
  bf16* lb = lds_b + wave * 512;
  const int sl = (quad ^ ((id >> 1) & 3)) * 8;   // swizzled read slot
  f32x4 acc[2][4] = {};
  for (int k0 = 0; k0 < kchunk; k0 += 64) {
    glds16(pa0, la);      glds16(pa1, la + 512);
    glds16(pa0 + 32, la + 4096); glds16(pa1 + 32, la + 4096 + 512);
    glds16(pb, lb);       glds16(pb + 32, lb + 2048);
    pa0 += 64; pa1 += 64; pb += 64;
    __syncthreads();
#pragma unroll
    for (int kh = 0; kh < 2; kh++) {
      bf16x8 af[2], bg[4];
#pragma unroll
      for (int i = 0; i < 2; i++)
        af[i] = *(bf16x8*)&lds_a[kh * 4096 + (wave * 32 + i * 16 + id) * 32 + sl];
#pragma unroll
      for (int j = 0; j < 4; j++)
        bg[j] = *(bf16x8*)&lds_b[kh * 2048 + (j * 16 + id) * 32 + sl];
#pragma unroll
      for (int i = 0; i < 2; i++)
#pragma unroll
        for (int j = 0; j < 4; j++)
          acc[i][j] = __builtin_amdgcn_mfma_f32_16x16x32_bf16(af[i], bg[j], acc[i][j], 0, 0, 0);
    }
    __syncthreads();
  }
#pragma unroll
  for (int i = 0; i < 2; i++) {
#pragma unroll
    for (int j = 0; j < 4; j++) {
#pragma unroll
      for (int r = 0; r < 4; r++) {
        int rr = m0 + wave * 32 + i * 16 + quad * 4 + r;
        int cc = n0 + j * 16 + id;
        if (mode == 4) {
          float v = acc[i][j][r] + (kz == 0 ? bias[cc] : 0.f);
          xout[slice + (size_t)rr * N + cc] = v;
        } else {
          float v = acc[i][j][r] + bias[cc];
          if (mode == 0) {
            outb[(size_t)rr * N + cc] = (bf16)v;
          } else if (mode == 1) {
            outb[(size_t)rr * N + cc] = (bf16)(0.5f * v * (1.0f + erff(v * 0.70710678f)));
          } else {
            xout[(size_t)rr * N + cc] = v + pos[(size_t)(rr & 511) * 768 + cc];
          }
        }
      }
    }
  }
}

// ---------------- fused phi_q: u=qs@proj^T, diag from sumsq, row-max, exp -> pq bf16 ----
__global__ __launch_bounds__(256) void phi_q_kernel(const bf16* __restrict__ qkv,
    const bf16* __restrict__ proj, bf16* __restrict__ pq) {
  __shared__ __attribute__((aligned(16))) bf16 lA[3][64 * 32];
  __shared__ __attribute__((aligned(16))) bf16 lB[3][256 * 32];
  __shared__ float sqlds[64];
  const int t = threadIdx.x;
  const int nt = blockIdx.x, bh = blockIdx.y;
  const int b = bh >> 3, h = bh & 7;
  const int n0 = nt * 64;
  const bf16* Abase = qkv + ((size_t)(b * 512 + n0)) * 2304 + h * 96;
#pragma unroll
  for (int c = 0; c < 3; c++) {
    int v = c * 256 + t;
    int row = v / 12, s = v % 12;
    *(bf16x8*)&lA[s >> 2][row * 32 + (s & 3) * 8] = *(const bf16x8*)&Abase[(size_t)row * 2304 + s * 8];
  }
#pragma unroll
  for (int c = 0; c < 12; c++) {
    int v = c * 256 + t;
    int row = v / 12, s = v % 12;
    *(bf16x8*)&lB[s >> 2][row * 32 + (s & 3) * 8] = *(const bf16x8*)&proj[(size_t)row * 96 + s * 8];
  }
  __syncthreads();
  const int wave = t >> 6, lane = t & 63, quad = lane >> 4, id = lane & 15;
  f32x4 acc[16] = {};
  float sq = 0.f;
#pragma unroll
  for (int kb = 0; kb < 3; kb++) {
    bf16x8 af = *(bf16x8*)&lA[kb][(wave * 16 + id) * 32 + quad * 8];
#pragma unroll
    for (int e = 0; e < 8; e++) { float fv = (float)af[e]; sq += fv * fv; }
#pragma unroll
    for (int j = 0; j < 16; j++) {
      bf16x8 bg = *(bf16x8*)&lB[kb][(j * 16 + id) * 32 + quad * 8];
      acc[j] = __builtin_amdgcn_mfma_f32_16x16x32_bf16(af, bg, acc[j], 0, 0, 0);
    }
  }
  sq += __shfl_xor(sq, 16, 64);
  sq += __shfl_xor(sq, 32, 64);
  if (quad == 0) sqlds[wave * 16 + id] = sq;
  __syncthreads();
#pragma unroll
  for (int r = 0; r < 4; r++) {
    int rrow = quad * 4 + r;
    float dg = DIAG_SCALE * sqlds[wave * 16 + rrow];
    float mx = -1e30f;
#pragma unroll
    for (int j = 0; j < 16; j++) mx = fmaxf(mx, acc[j][r]);
    mx = fmaxf(mx, __shfl_xor(mx, 1, 64));
    mx = fmaxf(mx, __shfl_xor(mx, 2, 64));
    mx = fmaxf(mx, __shfl_xor(mx, 4, 64));
    mx = fmaxf(mx, __shfl_xor(mx, 8, 64));
    float umax = mx * PHI_SCALE;
#pragma unroll
    for (int j = 0; j < 16; j++) {
      float uu = acc[j][r] * PHI_SCALE;
      float val = (expf(uu - dg - umax) + 1e-4f) * FEAT_SCALE;
      pq[((size_t)bh * 512 + n0 + wave * 16 + rrow) * 256 + j * 16 + id] = (bf16)val;
    }
  }
}

// ---------------- fused phi_k: u, diag, block-max; writes pkT TRANSPOSED directly -----
__global__ __launch_bounds__(256) void phi_k_kernel(const bf16* __restrict__ qkv,
    const bf16* __restrict__ proj, bf16* __restrict__ pkT, float* __restrict__ kbm) {
  __shared__ __attribute__((aligned(16))) bf16 lA[3][64 * 32];
  __shared__ __attribute__((aligned(16))) bf16 lB[3][256 * 32];
  __shared__ float sqlds[64];
  __shared__ float bmax4[4];
  const int t = threadIdx.x;
  const int nt = blockIdx.x, bh = blockIdx.y;
  const int b = bh >> 3, h = bh & 7;
  const int n0 = nt * 64;
  const bf16* Abase = qkv + ((size_t)(b * 512 + n0)) * 2304 + 768 + h * 96;
#pragma unroll
  for (int c = 0; c < 3; c++) {
    int v = c * 256 + t;
    int row = v / 12, s = v % 12;
    *(bf16x8*)&lA[s >> 2][row * 32 + (s & 3) * 8] = *(const bf16x8*)&Abase[(size_t)row * 2304 + s * 8];
  }
#pragma unroll
  for (int c = 0; c < 12; c++) {
    int v = c * 256 + t;
    int row = v / 12, s = v % 12;
    *(bf16x8*)&lB[s >> 2][row * 32 + (s & 3) * 8] = *(const bf16x8*)&proj[(size_t)row * 96 + s * 8];
  }
  __syncthreads();
  const int wave = t >> 6, lane = t & 63, quad = lane >> 4, id = lane & 15;
  f32x4 acc[16] = {};
  float sq = 0.f;
#pragma unroll
  for (int kb = 0; kb < 3; kb++) {
    bf16x8 af = *(bf16x8*)&lA[kb][(wave * 16 + id) * 32 + quad * 8];
#pragma unroll
    for (int e = 0; e < 8; e++) { float fv = (float)af[e]; sq += fv * fv; }
#pragma unroll
    for (int j = 0; j < 16; j++) {
      bf16x8 bg = *(bf16x8*)&lB[kb][(j * 16 + id) * 32 + quad * 8];
      acc[j] = __builtin_amdgcn_mfma_f32_16x16x32_bf16(af, bg, acc[j], 0, 0, 0);
    }
  }
  sq += __shfl_xor(sq, 16, 64);
  sq += __shfl_xor(sq, 32, 64);
  if (quad == 0) sqlds[wave * 16 + id] = sq;
  float bm = -1e30f;
#pragma unroll
  for (int j = 0; j < 16; j++)
#pragma unroll
    for (int r = 0; r < 4; r++) bm = fmaxf(bm, acc[j][r]);
  bm = waveMax(bm);
  if (lane == 0) bmax4[wave] = bm;
  __syncthreads();   // also guarantees all waves' MFMA reads of lB are done
  float blkmax = fmaxf(fmaxf(bmax4[0], bmax4[1]), fmaxf(bmax4[2], bmax4[3])) * PHI_SCALE;
  if (t == 0) kbm[bh * 8 + nt] = blkmax;
  // transpose through LDS (reuse dead lB: 256x66 bf16 = 33.8KB <= 48KB)
  bf16* sT = &lB[0][0];
#pragma unroll
  for (int r = 0; r < 4; r++) {
    int rrow = wave * 16 + quad * 4 + r;          // n within tile
    float dg = DIAG_SCALE * sqlds[rrow];
#pragma unroll
    for (int j = 0; j < 16; j++) {
      float uu = acc[j][r] * PHI_SCALE;
      sT[(j * 16 + id) * 66 + rrow] = (bf16)expf(uu - dg - blkmax);
    }
  }
  __syncthreads();
  bf16* dst = pkT + ((size_t)bh * 256) * 512 + n0;
#pragma unroll
  for (int it = 0; it < 64; it++) {
    int idx = it * 256 + t;
    int m = idx >> 6, n = idx & 63;
    dst[(size_t)m * 512 + n] = sT[m * 66 + n];
  }
}

// ---------------- vT[bh,e,n] = qkv[b,n,1536+h*96+e] ----------------
__global__ __launch_bounds__(256) void vt_kernel(const bf16* __restrict__ qkv, bf16* __restrict__ vT) {
  __shared__ bf16 lds[64][97];
  int bh = blockIdx.y, b = bh >> 3, h = bh & 7;
  int n0 = blockIdx.x * 64;
  int t = threadIdx.x;
  const bf16* src = qkv + ((size_t)b * 512 + n0) * 2304 + 1536 + h * 96;
  for (int idx = t; idx < 6144; idx += 256) {
    int r = idx / 96, c = idx % 96;
    lds[r][c] = src[(size_t)r * 2304 + c];
  }
  __syncthreads();
  bf16* dst = vT + (size_t)bh * 96 * 512 + n0;
  for (int idx = t; idx < 6144; idx += 256) {
    int e = idx >> 6, nn = idx & 63;
    dst[(size_t)e * 512 + nn] = lds[nn][e];
  }
}

// ---------------- ctx GEMM + fused rescale + ksum -----------------------------------
__global__ __launch_bounds__(256) void ctx_gemm(const bf16* __restrict__ pkT,
    const bf16* __restrict__ vT, const float* __restrict__ kbm,
    bf16* __restrict__ ctxT, float* __restrict__ ksum) {
  __shared__ __attribute__((aligned(16))) bf16 lds_a[64 * 40];
  __shared__ __attribute__((aligned(16))) bf16 lds_b[96 * 40];
  const int t = threadIdx.x;
  const int bh = blockIdx.y, m0 = blockIdx.x * 64;
  const bf16* A = pkT + (size_t)bh * 256 * 512;
  const bf16* B = vT + (size_t)bh * 96 * 512;
  const int wave = t >> 6, lane = t & 63;
  const int quad = lane >> 4, id = lane & 15;
  const int row = t >> 2, kof = (t & 3) * 8;
  float gm = blockMax(fmaxf(kbm[t], kbm[t + 256]));
  f32x4 acc[6] = {};
  float ks = 0.f;
  const float offc = 1e-4f * FEAT_SCALE;
  for (int k0 = 0; k0 < 512; k0 += 32) {
    float fs = expf(kbm[bh * 8 + (k0 >> 6)] - gm) * FEAT_SCALE;
    *(bf16x8*)&lds_a[row * 40 + kof] = *(const bf16x8*)&A[(size_t)(m0 + row) * 512 + k0 + kof];
    for (int idx = t; idx < 384; idx += 256) {
      int r2 = idx >> 2, k2 = (idx & 3) * 8;
      *(bf16x8*)&lds_b[r2 * 40 + k2] = *(const bf16x8*)&B[(size_t)r2 * 512 + k0 + k2];
    }
    __syncthreads();
    bf16x8 af = *(bf16x8*)&lds_a[(wave * 16 + id) * 40 + quad * 8];
    bf16x8 afs;
#pragma unroll
    for (int e = 0; e < 8; e++) {
      float f = (float)af[e] * fs + offc;
      ks += f;
      afs[e] = (bf16)f;
    }
#pragma unroll
    for (int j = 0; j < 6; j++) {
      bf16x8 bg = *(bf16x8*)&lds_b[(j * 16 + id) * 40 + quad * 8];
      acc[j] = __builtin_amdgcn_mfma_f32_16x16x32_bf16(afs, bg, acc[j], 0, 0, 0);
    }
    __syncthreads();
  }
  ks += __shfl_xor(ks, 16, 64);
  ks += __shfl_xor(ks, 32, 64);
  if (quad == 0) ksum[bh * 256 + m0 + wave * 16 + id] = ks;
#pragma unroll
  for (int j = 0; j < 6; j++)
#pragma unroll
    for (int r = 0; r < 4; r++) {
      int e = j * 16 + id;
      int m = m0 + wave * 16 + quad * 4 + r;
      ctxT[((size_t)bh * 96 + e) * 256 + m] = (bf16)acc[j][r];
    }
}

// ---------------- out GEMM + fused den: attn = (pq @ ctxT^T) / (pq . ksum) -------------
__global__ __launch_bounds__(256) void out_gemm(const bf16* __restrict__ pq,
    const bf16* __restrict__ ctxT, const float* __restrict__ ksum, bf16* __restrict__ attn) {
  __shared__ __attribute__((aligned(16))) bf16 lds_a[64 * 40];
  __shared__ __attribute__((aligned(16))) bf16 lds_b[96 * 40];
  __shared__ float den_lds[64];
  const int t = threadIdx.x;
  const int bh = blockIdx.y, m0 = blockIdx.x * 64;
  const int b = bh >> 3, h = bh & 7;
  const bf16* A = pq + (size_t)bh * 512 * 256;
  const bf16* B = ctxT + (size_t)bh * 96 * 256;
  const int wave = t >> 6, lane = t & 63;
  const int quad = lane >> 4, id = lane & 15;
  const int row = t >> 2, kof = (t & 3) * 8;
  f32x4 acc[6] = {};
  float den = 0.f;
  for (int k0 = 0; k0 < 256; k0 += 32) {
    *(bf16x8*)&lds_a[row * 40 + kof] = *(const bf16x8*)&A[(size_t)(m0 + row) * 256 + k0 + kof];
    for (int idx = t; idx < 384; idx += 256) {
      int r2 = idx >> 2, k2 = (idx & 3) * 8;
      *(bf16x8*)&lds_b[r2 * 40 + k2] = *(const bf16x8*)&B[(size_t)r2 * 256 + k0 + k2];
    }
    __syncthreads();
    bf16x8 af = *(bf16x8*)&lds_a[(wave * 16 + id) * 40 + quad * 8];
    const f32x4* kp = (const f32x4*)(ksum + bh * 256 + k0 + quad * 8);
    f32x4 k0v = kp[0], k1v = kp[1];
#pragma unroll
    for (int e = 0; e < 4; e++) den += (float)af[e] * k0v[e];
#pragma unroll
    for (int e = 0; e < 4; e++) den += (float)af[e + 4] * k1v[e];
#pragma unroll
    for (int j = 0; j < 6; j++) {
      bf16x8 bg = *(bf16x8*)&lds_b[(j * 16 + id) * 40 + quad * 8];
      acc[j] = __builtin_amdgcn_mfma_f32_16x16x32_bf16(af, bg, acc[j], 0, 0, 0);
    }
    __syncthreads();
  }
  den += __shfl_xor(den, 16, 64);
  den += __shfl_xor(den, 32, 64);
  if (quad == 0) den_lds[wave * 16 + id] = den;
  __syncthreads();
#pragma unroll
  for (int j = 0; j < 6; j++)
#pragma unroll
    for (int r = 0; r < 4; r++) {
      int e = j * 16 + id;
      int n = m0 + wave * 16 + quad * 4 + r;
      float v = acc[j][r] / fmaxf(den_lds[wave * 16 + quad * 4 + r], 1e-30f);
      attn[((size_t)(b * 512 + n)) * 768 + h * 96 + e] = (bf16)v;
    }
}

// ---------------- final head (+ ff2 partial fold) ----------------
__global__ __launch_bounds__(256) void mask_kernel(const float* __restrict__ x,
    const float* __restrict__ part,
    const float* __restrict__ mw, const float* __restrict__ mb, float* __restrict__ out) {
  int row = blockIdx.x * 4 + (threadIdx.x >> 6);
  int lane = threadIdx.x & 63;
  int b = row >> 9, n = row & 511;
  const float* xr = x + (size_t)row * 768;
  const float* p0 = part + (size_t)row * 768;
  const float* p1 = p0 + 4096ull * 768;
  float a0 = 0, a1 = 0, a2 = 0, a3 = 0;
  for (int d = lane; d < 768; d += 64) {
    float xv = xr[d] + p0[d] + p1[d];
    a0 += xv * mw[d * 4 + 0];
    a1 += xv * mw[d * 4 + 1];
    a2 += xv * mw[d * 4 + 2];
    a3 += xv * mw[d * 4 + 3];
  }
  a0 = waveSum(a0); a1 = waveSum(a1); a2 = waveSum(a2); a3 = waveSum(a3);
  if (lane == 0) {
    out[((size_t)b * 4 + 0) * 512 + n] = 1.f / (1.f + expf(-(a0 + mb[0])));
    out[((size_t)b * 4 + 1) * 512 + n] = 1.f / (1.f + expf(-(a1 + mb[1])));
    out[((size_t)b * 4 + 2) * 512 + n] = 1.f / (1.f + expf(-(a2 + mb[2])));
    out[((size_t)b * 4 + 3) * 512 + n] = 1.f / (1.f + expf(-(a3 + mb[3])));
  }
}

extern "C" void kernel_launch(void* const* d_in, const int* in_sizes, int n_in,
                              void* d_out, int out_size, void* d_ws, size_t ws_size,
                              hipStream_t stream) {
  const float* mel     = (const float*)d_in[0];
  const float* patch_w = (const float*)d_in[1];
  const float* patch_b = (const float*)d_in[2];
  const float* pos     = (const float*)d_in[3];
  const float* proj    = (const float*)d_in[4];
  const float* ln1_s   = (const float*)d_in[5];
  const float* ln1_b   = (const float*)d_in[6];
  const float* qkv_w   = (const float*)d_in[7];
  const float* qkv_b   = (const float*)d_in[8];
  const float* ao_w    = (const float*)d_in[9];
  const float* ao_b    = (const float*)d_in[10];
  const float* ln2_s   = (const float*)d_in[11];
  const float* ln2_b   = (const float*)d_in[12];
  const float* ff1_w   = (const float*)d_in[13];
  const float* ff1_b   = (const float*)d_in[14];
  const float* ff2_w   = (const float*)d_in[15];
  const float* ff2_b   = (const float*)d_in[16];
  const float* mask_w  = (const float*)d_in[17];
  const float* mask_b  = (const float*)d_in[18];

  char* ws = (char*)d_ws;
  size_t off = 0;
  auto alloc = [&](size_t bytes) { void* p = ws + off; off += (bytes + 255) & ~(size_t)255; return p; };
  float* x     = (float*)alloc(4096ull * 768 * 4);
  float* xpart = (float*)alloc(2ull * 4096 * 768 * 4);   // split-K partial slices
  bf16* h      = (bf16*)alloc(4096ull * 768 * 2);
  bf16* qkv    = (bf16*)alloc(4096ull * 2304 * 2);
  bf16* wtq    = (bf16*)alloc(2304ull * 768 * 2);
  bf16* wta    = (bf16*)alloc(768ull * 768 * 2);
  bf16* wtf1   = (bf16*)alloc(3072ull * 768 * 2);
  bf16* wtf2   = (bf16*)alloc(768ull * 3072 * 2);
  bf16* patches= (bf16*)alloc(4096ull * 256 * 2);
  bf16* pwb    = (bf16*)alloc(768ull * 256 * 2);
  bf16* projb  = (bf16*)alloc(256ull * 96 * 2);
  bf16* pq     = (bf16*)alloc(8388608ull * 2);
  bf16* pkT    = (bf16*)alloc(8388608ull * 2);
  bf16* vT     = (bf16*)alloc(64ull * 96 * 512 * 2);
  bf16* ctxT   = (bf16*)alloc(64ull * 96 * 256 * 2);
  float* ksum  = (float*)alloc(64ull * 256 * 4);
  float* kbm   = (float*)alloc(512ull * 4);
  bf16* attn   = (bf16*)alloc(4096ull * 768 * 2);
  bf16* ffh    = (bf16*)alloc(4096ull * 3072 * 2);
  if (ws_size < off) return;  // clean fail instead of corruption

  patches_kernel<<<4096, 256, 0, stream>>>(mel, patches);
  cvt_kernel<<<768, 256, 0, stream>>>(patch_w, pwb, 196608);
  cvt_kernel<<<96, 256, 0, stream>>>(proj, projb, 24576);
  gemm_b64<<<dim3(32, 12), 256, 0, stream>>>(patches, pwb, patch_b, nullptr, x, pos,
                                             768, 256, 3);

  for (int l = 0; l < 6; l++) {
    transpose4_kernel<<<1728, 256, 0, stream>>>(
        qkv_w + (size_t)l * 768 * 2304, wtq,
        ao_w + (size_t)l * 768 * 768, wta,
        ff1_w + (size_t)l * 768 * 3072, wtf1,
        ff2_w + (size_t)l * 3072 * 768, wtf2);

    // ln1: consumes prev layer's ff2 partials (none for l==0)
    ln_kernel<<<4096, 256, 0, stream>>>(x, l == 0 ? nullptr : xpart,
                                        ln1_s + l * 768, ln1_b + l * 768, h);
    // qkv: 128x128 tiles, (32,18) = 576 blocks
    gemm128<<<dim3(32, 18), 256, 0, stream>>>(h, wtq, qkv_b + l * 2304, qkv, 2304, 768, 0);

    phi_q_kernel<<<dim3(8, 64), 256, 0, stream>>>(qkv, projb, pq);
    phi_k_kernel<<<dim3(8, 64), 256, 0, stream>>>(qkv, projb, pkT, kbm);
    vt_kernel<<<dim3(8, 64), 256, 0, stream>>>(qkv, vT);
    ctx_gemm<<<dim3(4, 64), 256, 0, stream>>>(pkT, vT, kbm, ctxT, ksum);
    out_gemm<<<dim3(8, 64), 256, 0, stream>>>(pq, ctxT, ksum, attn);
    // attn @ ao_w + ao_b -> partials (split-K=2, non-atomic)
    gemm_b64<<<dim3(32, 12, 2), 256, 0, stream>>>(attn, wta, ao_b + l * 768, nullptr, xpart,
                                                  nullptr, 768, 384, 4);

    // ln2: folds ao partials into x, then LN
    ln_kernel<<<4096, 256, 0, stream>>>(x, xpart, ln2_s + l * 768, ln2_b + l * 768, h);
    // ff1: 128x128 tiles, (32,24) = 768 blocks
    gemm128<<<dim3(32, 24), 256, 0, stream>>>(h, wtf1, ff1_b + l * 3072, ffh, 3072, 768, 1);
    // ffh @ ff2_w + ff2_b -> partials (split-K=2, non-atomic)
    gemm_b64<<<dim3(32, 12, 2), 256, 0, stream>>>(ffh, wtf2, ff2_b + l * 768, nullptr, xpart,
                                                  nullptr, 768, 1536, 4);
  }

  mask_kernel<<<1024, 256, 0, stream>>>(x, xpart, mask_w, mask_b, (float*)d_out);
}

// Round 8
// 1322.513 us; speedup vs baseline: 1.2852x; 1.0405x over previous
//
#include <hip/hip_runtime.h>
#include <hip/hip_bf16.h>

typedef __bf16 bf16;
typedef __bf16 bf16x8 __attribute__((ext_vector_type(8)));
typedef float f32x4 __attribute__((ext_vector_type(4)));
typedef unsigned int u32;

#define PHI_SCALE  0.31947154f   // 96^-0.25
#define DIAG_SCALE 0.05103104f   // 0.5 * 96^-0.5
#define FEAT_SCALE 0.0625f       // 256^-0.5

// async global->LDS, 16B per lane; LDS dest = wave-uniform base + lane*16
__device__ __forceinline__ void glds16(const bf16* g, bf16* l) {
  __builtin_amdgcn_global_load_lds(
      (const __attribute__((address_space(1))) u32*)g,
      (__attribute__((address_space(3))) u32*)l, 16, 0, 0);
}

// XCD-aware 2D block swizzle (4 XCDs along M, 2 along N). Each XCD owns a
// contiguous (M/4 x N/2) region. Requires nbx%4==0, nby%2==0.
__device__ __forceinline__ void xcd_remap(int& bx, int& by) {
  int nbx = gridDim.x, nby = gridDim.y;
  int lin = bx + nbx * by;
  int xcd = lin & 7, idx = lin >> 3;
  int mloc = nbx >> 2, nloc = nby >> 1;
  int xm = xcd & 3, xn = xcd >> 2;
  bx = xm * mloc + (idx % mloc);
  by = xn * nloc + (idx / mloc);
}

// LDS bank swizzle (R4 measured: SQ_LDS_BANK_CONFLICT 3.5M -> 0 with this pair).
__device__ __forceinline__ int swz_scol(int lane) {   // stage: source col in elems
  return (((lane & 3) ^ ((lane >> 3) & 3)) * 8);
}

// ---------------- reductions ----------------
__device__ __forceinline__ float waveSum(float v) {
#pragma unroll
  for (int o = 32; o > 0; o >>= 1) v += __shfl_xor(v, o, 64);
  return v;
}
__device__ __forceinline__ float waveMax(float v) {
#pragma unroll
  for (int o = 32; o > 0; o >>= 1) v = fmaxf(v, __shfl_xor(v, o, 64));
  return v;
}
__device__ __forceinline__ float blockSum(float v) {
  __shared__ float tmp[4];
  v = waveSum(v);
  if ((threadIdx.x & 63) == 0) tmp[threadIdx.x >> 6] = v;
  __syncthreads();
  float r = tmp[0] + tmp[1] + tmp[2] + tmp[3];
  __syncthreads();
  return r;
}
__device__ __forceinline__ float blockMax(float v) {
  __shared__ float tmp[4];
  v = waveMax(v);
  if ((threadIdx.x & 63) == 0) tmp[threadIdx.x >> 6] = v;
  __syncthreads();
  float r = fmaxf(fmaxf(tmp[0], tmp[1]), fmaxf(tmp[2], tmp[3]));
  __syncthreads();
  return r;
}

// ---------------- patch gather: mel f32 -> patches bf16 (4096 x 256) ----------------
__global__ __launch_bounds__(256) void patches_kernel(const float* __restrict__ mel,
    bf16* __restrict__ patches) {
  int blk = blockIdx.x, t = threadIdx.x;
  int b = blk >> 9, n = blk & 511;
  int r0 = (n >> 3) << 4, c0 = (n & 7) << 4;
  patches[(size_t)blk * 256 + t] =
      (bf16)mel[((size_t)b * 1024 + r0 + (t >> 4)) * 128 + c0 + (t & 15)];
}

// ---------------- f32 -> bf16 convert ----------------
__global__ __launch_bounds__(256) void cvt_kernel(const float* __restrict__ src,
    bf16* __restrict__ dst, int n) {
  int i = blockIdx.x * 256 + threadIdx.x;
  if (i < n) dst[i] = (bf16)src[i];
}

// ---------------- merged per-layer weight transpose+cvt (4 weights, 1 dispatch) -------
__device__ __forceinline__ void tile_transpose(const float* __restrict__ src,
    bf16* __restrict__ dst, int K, int N, int bx, int by) {
  __shared__ float lds[64][65];
  int n0 = bx * 64, k0 = by * 64;
  int t = threadIdx.x;
  for (int idx = t; idx < 4096; idx += 256) {
    int r = idx >> 6, c = idx & 63;
    lds[r][c] = src[(size_t)(k0 + r) * N + n0 + c];
  }
  __syncthreads();
  for (int idx = t; idx < 4096; idx += 256) {
    int r = idx >> 6, c = idx & 63;
    dst[(size_t)(n0 + r) * K + k0 + c] = (bf16)lds[c][r];
  }
}
__global__ __launch_bounds__(256) void transpose4_kernel(
    const float* __restrict__ w0, bf16* __restrict__ d0,
    const float* __restrict__ w1, bf16* __restrict__ d1,
    const float* __restrict__ w2, bf16* __restrict__ d2,
    const float* __restrict__ w3, bf16* __restrict__ d3) {
  int i = blockIdx.x;
  if (i < 432)       { tile_transpose(w0, d0, 768, 2304, i % 36, i / 36); }          // qkv_w
  else if (i < 576)  { i -= 432;  tile_transpose(w1, d1, 768, 768, i % 12, i / 12); } // ao_w
  else if (i < 1152) { i -= 576;  tile_transpose(w2, d2, 768, 3072, i % 48, i / 48);} // ff1_w
  else               { i -= 1152; tile_transpose(w3, d3, 3072, 768, i % 12, i / 12);} // ff2_w
}

// ---------------- layernorm + optional residual fold: x += p0+p1; h = LN(x) ----------
__global__ __launch_bounds__(256) void ln_kernel(float* __restrict__ x,
    const float* __restrict__ part,
    const float* __restrict__ s, const float* __restrict__ bta, bf16* __restrict__ h) {
  int row = blockIdx.x;
  float* xr = x + (size_t)row * 768;
  int t = threadIdx.x;
  float v0 = xr[t], v1 = xr[t + 256], v2 = xr[t + 512];
  if (part) {
    const float* p0 = part + (size_t)row * 768;
    const float* p1 = p0 + 4096ull * 768;
    v0 += p0[t]       + p1[t];
    v1 += p0[t + 256] + p1[t + 256];
    v2 += p0[t + 512] + p1[t + 512];
    xr[t] = v0; xr[t + 256] = v1; xr[t + 512] = v2;
  }
  float mu = blockSum(v0 + v1 + v2) * (1.f / 768.f);
  float d0 = v0 - mu, d1 = v1 - mu, d2 = v2 - mu;
  float var = blockSum(d0 * d0 + d1 * d1 + d2 * d2) * (1.f / 768.f);
  float inv = rsqrtf(var + 1e-5f);
  bf16* hr = h + (size_t)row * 768;
  hr[t]       = (bf16)(d0 * inv * s[t]       + bta[t]);
  hr[t + 256] = (bf16)(d1 * inv * s[t + 256] + bta[t + 256]);
  hr[t + 512] = (bf16)(d2 * inv * s[t + 512] + bta[t + 512]);
}

// ---------------- big MFMA GEMM: BM=BN=128, BK=64 -----------------------------------
// mode 0: outb=bf16(v); 1: outb=bf16(gelu(v))
__global__ __launch_bounds__(256) void gemm128(const bf16* __restrict__ A,
    const bf16* __restrict__ B, const float* __restrict__ bias,
    bf16* __restrict__ outb, int N, int K, int mode) {
  __shared__ __attribute__((aligned(16))) bf16 lds_a[2 * 128 * 32];
  __shared__ __attribute__((aligned(16))) bf16 lds_b[2 * 128 * 32];
  int bx = blockIdx.x, by = blockIdx.y;
  xcd_remap(bx, by);
  const int t = threadIdx.x;
  const int m0 = bx * 128, n0 = by * 128;
  const int wave = t >> 6, lane = t & 63;
  const int quad = lane >> 4, id = lane & 15;
  const int wr = wave >> 1, wc = wave & 1;
  const int srow = lane >> 2, scol = swz_scol(lane);
  const bf16* pa0 = A + (size_t)(m0 + wave * 32 + srow) * K + scol;
  const bf16* pa1 = pa0 + (size_t)16 * K;
  const bf16* pb0 = B + (size_t)(n0 + wave * 32 + srow) * K + scol;
  const bf16* pb1 = pb0 + (size_t)16 * K;
  bf16* la = lds_a + wave * 1024;
  bf16* lb = lds_b + wave * 1024;
  const int sl = (quad ^ ((id >> 1) & 3)) * 8;   // swizzled read slot
  f32x4 acc[4][4] = {};
  for (int k0 = 0; k0 < K; k0 += 64) {
    glds16(pa0, la);      glds16(pa1, la + 512);
    glds16(pa0 + 32, la + 4096); glds16(pa1 + 32, la + 4096 + 512);
    glds16(pb0, lb);      glds16(pb1, lb + 512);
    glds16(pb0 + 32, lb + 4096); glds16(pb1 + 32, lb + 4096 + 512);
    pa0 += 64; pa1 += 64; pb0 += 64; pb1 += 64;
    __syncthreads();
#pragma unroll
    for (int kh = 0; kh < 2; kh++) {
      bf16x8 af[4], bg[4];
#pragma unroll
      for (int i = 0; i < 4; i++)
        af[i] = *(bf16x8*)&lds_a[kh * 4096 + (wr * 64 + i * 16 + id) * 32 + sl];
#pragma unroll
      for (int j = 0; j < 4; j++)
        bg[j] = *(bf16x8*)&lds_b[kh * 4096 + (wc * 64 + j * 16 + id) * 32 + sl];
#pragma unroll
      for (int i = 0; i < 4; i++)
#pragma unroll
        for (int j = 0; j < 4; j++)
          acc[i][j] = __builtin_amdgcn_mfma_f32_16x16x32_bf16(af[i], bg[j], acc[i][j], 0, 0, 0);
    }
    __syncthreads();
  }
#pragma unroll
  for (int i = 0; i < 4; i++) {
#pragma unroll
    for (int j = 0; j < 4; j++) {
#pragma unroll
      for (int r = 0; r < 4; r++) {
        int rr = m0 + wr * 64 + i * 16 + quad * 4 + r;
        int cc = n0 + wc * 64 + j * 16 + id;
        float v = acc[i][j][r] + bias[cc];
        if (mode == 1) v = 0.5f * v * (1.0f + erff(v * 0.70710678f));
        outb[(size_t)rr * N + cc] = (bf16)v;
      }
    }
  }
}

// ---------------- MFMA GEMM: BM=128, BN=64, BK=64 -----------------------------------
// mode 0: outb=bf16(v); 1: outb=bf16(gelu(v)); 3: xout=v+pos;
// mode 4: NON-ATOMIC partial write: xout[kz*M*N + rr*N + cc] = v (+bias if kz==0).
__global__ __launch_bounds__(256) void gemm_b64(const bf16* __restrict__ A,
    const bf16* __restrict__ B, const float* __restrict__ bias,
    bf16* __restrict__ outb, float* __restrict__ xout,
    const float* __restrict__ pos, int N, int kchunk, int mode) {
  __shared__ __attribute__((aligned(16))) bf16 lds_a[2 * 128 * 32];
  __shared__ __attribute__((aligned(16))) bf16 lds_b[2 * 64 * 32];
  int bx = blockIdx.x, by = blockIdx.y;
  xcd_remap(bx, by);
  const int t = threadIdx.x;
  const int m0 = bx * 128, n0 = by * 64;
  const int kz = blockIdx.z;
  const int k_start = kz * kchunk;
  const int wave = t >> 6, lane = t & 63;
  const int quad = lane >> 4, id = lane & 15;
  const int srow = lane >> 2, scol = swz_scol(lane);
  const int K = kchunk * gridDim.z;
  const size_t slice = (size_t)kz * gridDim.x * 128 * N;
  const bf16* pa0 = A + (size_t)(m0 + wave * 32 + srow) * K + k_start + scol;
  const bf16* pa1 = pa0 + (size_t)16 * K;
  const bf16* pb  = B + (size_t)(n0 + wave * 16 + srow) * K + k_start + scol;
  bf16* la = lds_a + wave * 1024;
  bf16* lb = lds_b + wave * 512;
  const int sl = (quad ^ ((id >> 1) & 3)) * 8;   // swizzled read slot
  f32x4 acc[2][4] = {};
  for (int k0 = 0; k0 < kchunk; k0 += 64) {
    glds16(pa0, la);      glds16(pa1, la + 512);
    glds16(pa0 + 32, la + 4096); glds16(pa1 + 32, la + 4096 + 512);
    glds16(pb, lb);       glds16(pb + 32, lb + 2048);
    pa0 += 64; pa1 += 64; pb += 64;
    __syncthreads();
#pragma unroll
    for (int kh = 0; kh < 2; kh++) {
      bf16x8 af[2], bg[4];
#pragma unroll
      for (int i = 0; i < 2; i++)
        af[i] = *(bf16x8*)&lds_a[kh * 4096 + (wave * 32 + i * 16 + id) * 32 + sl];
#pragma unroll
      for (int j = 0; j < 4; j++)
        bg[j] = *(bf16x8*)&lds_b[kh * 2048 + (j * 16 + id) * 32 + sl];
#pragma unroll
      for (int i = 0; i < 2; i++)
#pragma unroll
        for (int j = 0; j < 4; j++)
          acc[i][j] = __builtin_amdgcn_mfma_f32_16x16x32_bf16(af[i], bg[j], acc[i][j], 0, 0, 0);
    }
    __syncthreads();
  }
#pragma unroll
  for (int i = 0; i < 2; i++) {
#pragma unroll
    for (int j = 0; j < 4; j++) {
#pragma unroll
      for (int r = 0; r < 4; r++) {
        int rr = m0 + wave * 32 + i * 16 + quad * 4 + r;
        int cc = n0 + j * 16 + id;
        if (mode == 4) {
          float v = acc[i][j][r] + (kz == 0 ? bias[cc] : 0.f);
          xout[slice + (size_t)rr * N + cc] = v;
        } else {
          float v = acc[i][j][r] + bias[cc];
          if (mode == 0) {
            outb[(size_t)rr * N + cc] = (bf16)v;
          } else if (mode == 1) {
            outb[(size_t)rr * N + cc] = (bf16)(0.5f * v * (1.0f + erff(v * 0.70710678f)));
          } else {
            xout[(size_t)rr * N + cc] = v + pos[(size_t)(rr & 511) * 768 + cc];
          }
        }
      }
    }
  }
}

// ---------------- fused phi: Q-phase, K-phase, V-transpose in ONE kernel -------------
// Replaces phi_q + phi_k + vt. proj staged ONCE (48KB -> 3 blocks/CU, was 2 at
// 60KB); Q/K A-fragments loaded DIRECT from global (each fragment used once per
// wave -- the old LDS round-trip had zero reuse). After K's MFMAs the dead proj
// LDS is reused as the pkT-transpose buffer (256x66) + V-transpose buffer (64x97).
__global__ __launch_bounds__(256) void phi_fused(const bf16* __restrict__ qkv,
    const bf16* __restrict__ proj, bf16* __restrict__ pq,
    bf16* __restrict__ pkT, float* __restrict__ kbm, bf16* __restrict__ vT) {
  __shared__ __attribute__((aligned(16))) bf16 smem[3 * 256 * 32];   // 48KB
  __shared__ float sqlds[64];
  __shared__ float bmax4[4];
  const int t = threadIdx.x;
  const int nt = blockIdx.x, bh = blockIdx.y;
  const int b = bh >> 3, h = bh & 7;
  const int n0 = nt * 64;
  // stage proj (reused by Q and K phases)
#pragma unroll
  for (int c = 0; c < 12; c++) {
    int v = c * 256 + t;
    int row = v / 12, s = v % 12;
    *(bf16x8*)&smem[(s >> 2) * 8192 + row * 32 + (s & 3) * 8] =
        *(const bf16x8*)&proj[(size_t)row * 96 + s * 8];
  }
  __syncthreads();
  const int wave = t >> 6, lane = t & 63, quad = lane >> 4, id = lane & 15;
  const bf16* qrow = qkv + ((size_t)(b * 512 + n0 + wave * 16 + id)) * 2304 + h * 96;

  // ---------- phase Q ----------
  {
    f32x4 acc[16] = {};
    float sq = 0.f;
#pragma unroll
    for (int kb = 0; kb < 3; kb++) {
      bf16x8 af = *(const bf16x8*)&qrow[kb * 32 + quad * 8];
#pragma unroll
      for (int e = 0; e < 8; e++) { float fv = (float)af[e]; sq += fv * fv; }
#pragma unroll
      for (int j = 0; j < 16; j++) {
        bf16x8 bg = *(bf16x8*)&smem[kb * 8192 + (j * 16 + id) * 32 + quad * 8];
        acc[j] = __builtin_amdgcn_mfma_f32_16x16x32_bf16(af, bg, acc[j], 0, 0, 0);
      }
    }
    sq += __shfl_xor(sq, 16, 64);
    sq += __shfl_xor(sq, 32, 64);
    if (quad == 0) sqlds[wave * 16 + id] = sq;
    __syncthreads();
#pragma unroll
    for (int r = 0; r < 4; r++) {
      int rrow = quad * 4 + r;
      float dg = DIAG_SCALE * sqlds[wave * 16 + rrow];
      float mx = -1e30f;
#pragma unroll
      for (int j = 0; j < 16; j++) mx = fmaxf(mx, acc[j][r]);
      mx = fmaxf(mx, __shfl_xor(mx, 1, 64));
      mx = fmaxf(mx, __shfl_xor(mx, 2, 64));
      mx = fmaxf(mx, __shfl_xor(mx, 4, 64));
      mx = fmaxf(mx, __shfl_xor(mx, 8, 64));
      float umax = mx * PHI_SCALE;
#pragma unroll
      for (int j = 0; j < 16; j++) {
        float uu = acc[j][r] * PHI_SCALE;
        float val = (expf(uu - dg - umax) + 1e-4f) * FEAT_SCALE;
        pq[((size_t)bh * 512 + n0 + wave * 16 + rrow) * 256 + j * 16 + id] = (bf16)val;
      }
    }
  }
  __syncthreads();   // sqlds WAR protection (Q epilogue reads done)

  // ---------- phase K ----------
  {
    f32x4 acc[16] = {};
    float sq = 0.f;
#pragma unroll
    for (int kb = 0; kb < 3; kb++) {
      bf16x8 af = *(const bf16x8*)&qrow[768 + kb * 32 + quad * 8];
#pragma unroll
      for (int e = 0; e < 8; e++) { float fv = (float)af[e]; sq += fv * fv; }
#pragma unroll
      for (int j = 0; j < 16; j++) {
        bf16x8 bg = *(bf16x8*)&smem[kb * 8192 + (j * 16 + id) * 32 + quad * 8];
        acc[j] = __builtin_amdgcn_mfma_f32_16x16x32_bf16(af, bg, acc[j], 0, 0, 0);
      }
    }
    sq += __shfl_xor(sq, 16, 64);
    sq += __shfl_xor(sq, 32, 64);
    if (quad == 0) sqlds[wave * 16 + id] = sq;
    float bm = -1e30f;
#pragma unroll
    for (int j = 0; j < 16; j++)
#pragma unroll
      for (int r = 0; r < 4; r++) bm = fmaxf(bm, acc[j][r]);
    bm = waveMax(bm);
    if (lane == 0) bmax4[wave] = bm;
    __syncthreads();   // all MFMA reads of smem done; sqlds/bmax4 visible
    float blkmax = fmaxf(fmaxf(bmax4[0], bmax4[1]), fmaxf(bmax4[2], bmax4[3])) * PHI_SCALE;
    if (t == 0) kbm[bh * 8 + nt] = blkmax;
    // reuse dead proj LDS: sT = smem[0 .. 16895] (256x66), vlds = smem[16896 ..] (64x97)
    bf16* sT = smem;
    bf16* vlds = smem + 16896;
#pragma unroll
    for (int r = 0; r < 4; r++) {
      int rrow = wave * 16 + quad * 4 + r;          // n within tile
      float dg = DIAG_SCALE * sqlds[rrow];
#pragma unroll
      for (int j = 0; j < 16; j++) {
        float uu = acc[j][r] * PHI_SCALE;
        sT[(j * 16 + id) * 66 + rrow] = (bf16)expf(uu - dg - blkmax);
      }
    }
    // V load (overlaps sT VALU work with global-read latency)
    const bf16* vsrc = qkv + ((size_t)(b * 512 + n0)) * 2304 + 1536 + h * 96;
    for (int idx = t; idx < 6144; idx += 256) {
      int r = idx / 96, c = idx % 96;
      vlds[r * 97 + c] = vsrc[(size_t)r * 2304 + c];
    }
    __syncthreads();
    // pkT write (transposed): pkT[bh][m][n0+n]
    bf16* dst = pkT + ((size_t)bh * 256) * 512 + n0;
#pragma unroll
    for (int it = 0; it < 64; it++) {
      int idx = it * 256 + t;
      int m = idx >> 6, n = idx & 63;
      dst[(size_t)m * 512 + n] = sT[m * 66 + n];
    }
    // vT write: vT[bh][e][n0+nn]
    bf16* vdst = vT + (size_t)bh * 96 * 512 + n0;
    for (int idx = t; idx < 6144; idx += 256) {
      int e = idx >> 6, nn = idx & 63;
      vdst[(size_t)e * 512 + nn] = vlds[nn * 97 + e];
    }
  }
}

// ---------------- ctx GEMM + fused rescale + ksum (A direct from global) --------------
__global__ __launch_bounds__(256) void ctx_gemm(const bf16* __restrict__ pkT,
    const bf16* __restrict__ vT, const float* __restrict__ kbm,
    bf16* __restrict__ ctxT, float* __restrict__ ksum) {
  __shared__ __attribute__((aligned(16))) bf16 lds_b[96 * 40];
  const int t = threadIdx.x;
  const int bh = blockIdx.y, m0 = blockIdx.x * 64;
  const bf16* A = pkT + (size_t)bh * 256 * 512;
  const bf16* B = vT + (size_t)bh * 96 * 512;
  const int wave = t >> 6, lane = t & 63;
  const int quad = lane >> 4, id = lane & 15;
  float gm = blockMax(fmaxf(kbm[t], kbm[t + 256]));
  f32x4 acc[6] = {};
  float ks = 0.f;
  const float offc = 1e-4f * FEAT_SCALE;
  const bf16* arow = A + (size_t)(m0 + wave * 16 + id) * 512 + quad * 8;
  for (int k0 = 0; k0 < 512; k0 += 32) {
    float fs = expf(kbm[bh * 8 + (k0 >> 6)] - gm) * FEAT_SCALE;
    for (int idx = t; idx < 384; idx += 256) {
      int r2 = idx >> 2, k2 = (idx & 3) * 8;
      *(bf16x8*)&lds_b[r2 * 40 + k2] = *(const bf16x8*)&B[(size_t)r2 * 512 + k0 + k2];
    }
    bf16x8 af = *(const bf16x8*)&arow[k0];
    __syncthreads();
    bf16x8 afs;
#pragma unroll
    for (int e = 0; e < 8; e++) {
      float f = (float)af[e] * fs + offc;
      ks += f;
      afs[e] = (bf16)f;
    }
#pragma unroll
    for (int j = 0; j < 6; j++) {
      bf16x8 bg = *(bf16x8*)&lds_b[(j * 16 + id) * 40 + quad * 8];
      acc[j] = __builtin_amdgcn_mfma_f32_16x16x32_bf16(afs, bg, acc[j], 0, 0, 0);
    }
    __syncthreads();
  }
  ks += __shfl_xor(ks, 16, 64);
  ks += __shfl_xor(ks, 32, 64);
  if (quad == 0) ksum[bh * 256 + m0 + wave * 16 + id] = ks;
#pragma unroll
  for (int j = 0; j < 6; j++)
#pragma unroll
    for (int r = 0; r < 4; r++) {
      int e = j * 16 + id;
      int m = m0 + wave * 16 + quad * 4 + r;
      ctxT[((size_t)bh * 96 + e) * 256 + m] = (bf16)acc[j][r];
    }
}

// ---------------- out GEMM + fused den (A direct from global) -------------------------
__global__ __launch_bounds__(256) void out_gemm(const bf16* __restrict__ pq,
    const bf16* __restrict__ ctxT, const float* __restrict__ ksum, bf16* __restrict__ attn) {
  __shared__ __attribute__((aligned(16))) bf16 lds_b[96 * 40];
  __shared__ float den_lds[64];
  const int t = threadIdx.x;
  const int bh = blockIdx.y, m0 = blockIdx.x * 64;
  const int b = bh >> 3, h = bh & 7;
  const bf16* A = pq + (size_t)bh * 512 * 256;
  const bf16* B = ctxT + (size_t)bh * 96 * 256;
  const int wave = t >> 6, lane = t & 63;
  const int quad = lane >> 4, id = lane & 15;
  f32x4 acc[6] = {};
  float den = 0.f;
  const bf16* arow = A + (size_t)(m0 + wave * 16 + id) * 256 + quad * 8;
  for (int k0 = 0; k0 < 256; k0 += 32) {
    for (int idx = t; idx < 384; idx += 256) {
      int r2 = idx >> 2, k2 = (idx & 3) * 8;
      *(bf16x8*)&lds_b[r2 * 40 + k2] = *(const bf16x8*)&B[(size_t)r2 * 256 + k0 + k2];
    }
    bf16x8 af = *(const bf16x8*)&arow[k0];
    __syncthreads();
    const f32x4* kp = (const f32x4*)(ksum + bh * 256 + k0 + quad * 8);
    f32x4 k0v = kp[0], k1v = kp[1];
#pragma unroll
    for (int e = 0; e < 4; e++) den += (float)af[e] * k0v[e];
#pragma unroll
    for (int e = 0; e < 4; e++) den += (float)af[e + 4] * k1v[e];
#pragma unroll
    for (int j = 0; j < 6; j++) {
      bf16x8 bg = *(bf16x8*)&lds_b[(j * 16 + id) * 40 + quad * 8];
      acc[j] = __builtin_amdgcn_mfma_f32_16x16x32_bf16(af, bg, acc[j], 0, 0, 0);
    }
    __syncthreads();
  }
  den += __shfl_xor(den, 16, 64);
  den += __shfl_xor(den, 32, 64);
  if (quad == 0) den_lds[wave * 16 + id] = den;
  __syncthreads();
#pragma unroll
  for (int j = 0; j < 6; j++)
#pragma unroll
    for (int r = 0; r < 4; r++) {
      int e = j * 16 + id;
      int n = m0 + wave * 16 + quad * 4 + r;
      float v = acc[j][r] / fmaxf(den_lds[wave * 16 + quad * 4 + r], 1e-30f);
      attn[((size_t)(b * 512 + n)) * 768 + h * 96 + e] = (bf16)v;
    }
}

// ---------------- final head (+ ff2 partial fold) ----------------
__global__ __launch_bounds__(256) void mask_kernel(const float* __restrict__ x,
    const float* __restrict__ part,
    const float* __restrict__ mw, const float* __restrict__ mb, float* __restrict__ out) {
  int row = blockIdx.x * 4 + (threadIdx.x >> 6);
  int lane = threadIdx.x & 63;
  int b = row >> 9, n = row & 511;
  const float* xr = x + (size_t)row * 768;
  const float* p0 = part + (size_t)row * 768;
  const float* p1 = p0 + 4096ull * 768;
  float a0 = 0, a1 = 0, a2 = 0, a3 = 0;
  for (int d = lane; d < 768; d += 64) {
    float xv = xr[d] + p0[d] + p1[d];
    a0 += xv * mw[d * 4 + 0];
    a1 += xv * mw[d * 4 + 1];
    a2 += xv * mw[d * 4 + 2];
    a3 += xv * mw[d * 4 + 3];
  }
  a0 = waveSum(a0); a1 = waveSum(a1); a2 = waveSum(a2); a3 = waveSum(a3);
  if (lane == 0) {
    out[((size_t)b * 4 + 0) * 512 + n] = 1.f / (1.f + expf(-(a0 + mb[0])));
    out[((size_t)b * 4 + 1) * 512 + n] = 1.f / (1.f + expf(-(a1 + mb[1])));
    out[((size_t)b * 4 + 2) * 512 + n] = 1.f / (1.f + expf(-(a2 + mb[2])));
    out[((size_t)b * 4 + 3) * 512 + n] = 1.f / (1.f + expf(-(a3 + mb[3])));
  }
}

extern "C" void kernel_launch(void* const* d_in, const int* in_sizes, int n_in,
                              void* d_out, int out_size, void* d_ws, size_t ws_size,
                              hipStream_t stream) {
  const float* mel     = (const float*)d_in[0];
  const float* patch_w = (const float*)d_in[1];
  const float* patch_b = (const float*)d_in[2];
  const float* pos     = (const float*)d_in[3];
  const float* proj    = (const float*)d_in[4];
  const float* ln1_s   = (const float*)d_in[5];
  const float* ln1_b   = (const float*)d_in[6];
  const float* qkv_w   = (const float*)d_in[7];
  const float* qkv_b   = (const float*)d_in[8];
  const float* ao_w    = (const float*)d_in[9];
  const float* ao_b    = (const float*)d_in[10];
  const float* ln2_s   = (const float*)d_in[11];
  const float* ln2_b   = (const float*)d_in[12];
  const float* ff1_w   = (const float*)d_in[13];
  const float* ff1_b   = (const float*)d_in[14];
  const float* ff2_w   = (const float*)d_in[15];
  const float* ff2_b   = (const float*)d_in[16];
  const float* mask_w  = (const float*)d_in[17];
  const float* mask_b  = (const float*)d_in[18];

  char* ws = (char*)d_ws;
  size_t off = 0;
  auto alloc = [&](size_t bytes) { void* p = ws + off; off += (bytes + 255) & ~(size_t)255; return p; };
  float* x     = (float*)alloc(4096ull * 768 * 4);
  float* xpart = (float*)alloc(2ull * 4096 * 768 * 4);   // split-K partial slices
  bf16* h      = (bf16*)alloc(4096ull * 768 * 2);
  bf16* qkv    = (bf16*)alloc(4096ull * 2304 * 2);
  bf16* wtq    = (bf16*)alloc(2304ull * 768 * 2);
  bf16* wta    = (bf16*)alloc(768ull * 768 * 2);
  bf16* wtf1   = (bf16*)alloc(3072ull * 768 * 2);
  bf16* wtf2   = (bf16*)alloc(768ull * 3072 * 2);
  bf16* patches= (bf16*)alloc(4096ull * 256 * 2);
  bf16* pwb    = (bf16*)alloc(768ull * 256 * 2);
  bf16* projb  = (bf16*)alloc(256ull * 96 * 2);
  bf16* pq     = (bf16*)alloc(8388608ull * 2);
  bf16* pkT    = (bf16*)alloc(8388608ull * 2);
  bf16* vT     = (bf16*)alloc(64ull * 96 * 512 * 2);
  bf16* ctxT   = (bf16*)alloc(64ull * 96 * 256 * 2);
  float* ksum  = (float*)alloc(64ull * 256 * 4);
  float* kbm   = (float*)alloc(512ull * 4);
  bf16* attn   = (bf16*)alloc(4096ull * 768 * 2);
  bf16* ffh    = (bf16*)alloc(4096ull * 3072 * 2);
  if (ws_size < off) return;  // clean fail instead of corruption

  patches_kernel<<<4096, 256, 0, stream>>>(mel, patches);
  cvt_kernel<<<768, 256, 0, stream>>>(patch_w, pwb, 196608);
  cvt_kernel<<<96, 256, 0, stream>>>(proj, projb, 24576);
  gemm_b64<<<dim3(32, 12), 256, 0, stream>>>(patches, pwb, patch_b, nullptr, x, pos,
                                             768, 256, 3);

  for (int l = 0; l < 6; l++) {
    transpose4_kernel<<<1728, 256, 0, stream>>>(
        qkv_w + (size_t)l * 768 * 2304, wtq,
        ao_w + (size_t)l * 768 * 768, wta,
        ff1_w + (size_t)l * 768 * 3072, wtf1,
        ff2_w + (size_t)l * 3072 * 768, wtf2);

    // ln1: consumes prev layer's ff2 partials (none for l==0)
    ln_kernel<<<4096, 256, 0, stream>>>(x, l == 0 ? nullptr : xpart,
                                        ln1_s + l * 768, ln1_b + l * 768, h);
    // qkv: 128x128 tiles, (32,18) = 576 blocks
    gemm128<<<dim3(32, 18), 256, 0, stream>>>(h, wtq, qkv_b + l * 2304, qkv, 2304, 768, 0);

    // fused phi_q + phi_k + vT: one dispatch
    phi_fused<<<dim3(8, 64), 256, 0, stream>>>(qkv, projb, pq, pkT, kbm, vT);
    ctx_gemm<<<dim3(4, 64), 256, 0, stream>>>(pkT, vT, kbm, ctxT, ksum);
    out_gemm<<<dim3(8, 64), 256, 0, stream>>>(pq, ctxT, ksum, attn);
    // attn @ ao_w + ao_b -> partials (split-K=2, non-atomic)
    gemm_b64<<<dim3(32, 12, 2), 256, 0, stream>>>(attn, wta, ao_b + l * 768, nullptr, xpart,
                                                  nullptr, 768, 384, 4);

    // ln2: folds ao partials into x, then LN
    ln_kernel<<<4096, 256, 0, stream>>>(x, xpart, ln2_s + l * 768, ln2_b + l * 768, h);
    // ff1: 128x128 tiles, (32,24) = 768 blocks
    gemm128<<<dim3(32, 24), 256, 0, stream>>>(h, wtf1, ff1_b + l * 3072, ffh, 3072, 768, 1);
    // ffh @ ff2_w + ff2_b -> partials (split-K=2, non-atomic)
    gemm_b64<<<dim3(32, 12, 2), 256, 0, stream>>>(ffh, wtf2, ff2_b + l * 768, nullptr, xpart,
                                                  nullptr, 768, 1536, 4);
  }

  mask_kernel<<<1024, 256, 0, stream>>>(x, xpart, mask_w, mask_b, (float*)d_out);
}